// Round 7
// baseline (822.207 us; speedup 1.0000x reference)
//
#include <hip/hip_runtime.h>
#include <hip/hip_fp16.h>

#define HC 128
#define EPS_BN 1e-5f
#define NSTRIPE 8
#define AGG_BLOCKS 3072
#define BSHIFT 7                 // 128 nodes per bucket
#define BNODES (1 << BSHIFT)

typedef _Float16 f16;
typedef f16  f16x8 __attribute__((ext_vector_type(8)));
typedef float f32x4 __attribute__((ext_vector_type(4)));

// ---------------- degree count (int) ----------------
__global__ void degi_kernel(const int* __restrict__ dst, int* __restrict__ degi, int E) {
    int e = blockIdx.x * 256 + threadIdx.x;
    if (e < E) atomicAdd(&degi[dst[e]], 1);
}

__global__ void dis_kernel(const int* __restrict__ degi, float* __restrict__ dis, int n) {
    int i = blockIdx.x * 256 + threadIdx.x;
    if (i < n) dis[i] = rsqrtf((float)degi[i] + 1.0f);  // +1 self-loop
}

// ---------------- exclusive scan of degi -> rowptr ----------------
__global__ __launch_bounds__(256) void scan1(const int* __restrict__ degi, int* __restrict__ excl,
                                             int* __restrict__ bsums, int n) {
    __shared__ int ts[256];
    const int tid = threadIdx.x;
    const int base = blockIdx.x * 1024 + tid * 4;
    int v0 = 0, v1 = 0, v2 = 0, v3 = 0;
    if (base + 3 < n) {
        int4 v = *(const int4*)(degi + base);
        v0 = v.x; v1 = v.y; v2 = v.z; v3 = v.w;
    } else {
        if (base + 0 < n) v0 = degi[base + 0];
        if (base + 1 < n) v1 = degi[base + 1];
        if (base + 2 < n) v2 = degi[base + 2];
        if (base + 3 < n) v3 = degi[base + 3];
    }
    int p1 = v0, p2 = v0 + v1, p3 = v0 + v1 + v2, total = p3 + v3;
    ts[tid] = total;
    __syncthreads();
    for (int off = 1; off < 256; off <<= 1) {
        int t = (tid >= off) ? ts[tid - off] : 0;
        __syncthreads();
        ts[tid] += t;
        __syncthreads();
    }
    int eb = (tid ? ts[tid - 1] : 0);
    if (tid == 255) bsums[blockIdx.x] = ts[255];
    if (base + 0 < n) excl[base + 0] = eb;
    if (base + 1 < n) excl[base + 1] = eb + p1;
    if (base + 2 < n) excl[base + 2] = eb + p2;
    if (base + 3 < n) excl[base + 3] = eb + p3;
}

__global__ void scan2(int* __restrict__ bsums, int nb) {
    if (threadIdx.x == 0) {
        int s = 0;
        for (int i = 0; i < nb; ++i) { int t = bsums[i]; bsums[i] = s; s += t; }
    }
}

__global__ void scan3(const int* __restrict__ excl, const int* __restrict__ bsums,
                      int* __restrict__ rowptr, int n, int E) {
    int i = blockIdx.x * 256 + threadIdx.x;
    if (i < n) rowptr[i] = excl[i] + bsums[i >> 10];
    if (i == n) rowptr[n] = E;
}

// ---------------- bucket cursor init from rowptr (free histogram) -----------
__global__ void binit(const int* __restrict__ rowptr, int* __restrict__ cur1, int nb, int n) {
    int b = blockIdx.x * 256 + threadIdx.x;
    if (b < nb) {
        int node0 = b << BSHIFT;
        cur1[b] = rowptr[node0 < n ? node0 : n];
    }
}

// ---------------- pass 1: bucket append {src,dst} ---------------------------
__global__ void edge_bucket(const int* __restrict__ src, const int* __restrict__ dst,
                            int* __restrict__ cur1, int2* __restrict__ bucketed, int E) {
    int e = blockIdx.x * 256 + threadIdx.x;
    if (e < E) {
        int s = src[e], d = dst[e];
        int pos = atomicAdd(&cur1[d >> BSHIFT], 1);
        bucketed[pos] = make_int2(s, d);
    }
}

// ---------------- pass 2: within-bucket exact CSR placement -----------------
__global__ __launch_bounds__(256) void edge_sort(const int2* __restrict__ bucketed,
                                                 const int* __restrict__ rowptr,
                                                 int* __restrict__ srcs, int n) {
    __shared__ int cur[BNODES];
    const int b = blockIdx.x;
    const int node0 = b << BSHIFT;
    const int nodeEnd = min(node0 + BNODES, n);
    const int tid = threadIdx.x;
    if (tid < BNODES && node0 + tid < n) cur[tid] = rowptr[node0 + tid];
    __syncthreads();
    const int e0 = rowptr[node0];
    const int e1 = rowptr[nodeEnd];
    for (int e = e0 + tid; e < e1; e += 256) {
        int2 p = bucketed[e];
        int pos = atomicAdd(&cur[p.y & (BNODES - 1)], 1);
        srcs[pos] = p.x;
    }
}

// ---------------- W transpose + fp16 convert: Wt[c][k] = W[k][c] ------------
__global__ void wprep(const float* __restrict__ W, f16* __restrict__ Wt) {
    int idx = blockIdx.x * 256 + threadIdx.x;   // 16384 total
    if (idx < HC * HC) {
        int k = idx >> 7, c = idx & 127;
        Wt[(size_t)c * HC + k] = (f16)W[idx];
    }
}

// ---------------- MFMA GEMM: Y[n,128](f16) = T(X)[n,128] @ W[128,128] -------
template<int SRC_F16, int TRANS>
__global__ __launch_bounds__(256) void gemm_mfma(const void* __restrict__ Xv,
                                                 const f16* __restrict__ Wt,
                                                 const float* __restrict__ scale,
                                                 const float* __restrict__ shift,
                                                 f16* __restrict__ Y, int n) {
    __shared__ f16 Ah[64][136];
    __shared__ f16 Bh[128][136];
    const int tid  = threadIdx.x;
    const int row0 = blockIdx.x * 64;

#pragma unroll
    for (int i = 0; i < 8; ++i) {
        int idx = i * 256 + tid;
        int r = idx >> 4, g = idx & 15;
        *(f16x8*)&Bh[r][g * 8] = *(const f16x8*)(Wt + (size_t)r * HC + g * 8);
    }
#pragma unroll
    for (int i = 0; i < 4; ++i) {
        int idx = i * 256 + tid;
        int r = idx >> 4, g = idx & 15;
        int grow = row0 + r;
        f16x8 h = {};
        if (grow < n) {
            if constexpr (SRC_F16) {
                f16x8 v = *(const f16x8*)((const f16*)Xv + (size_t)grow * HC + g * 8);
                if constexpr (TRANS) {
#pragma unroll
                    for (int j = 0; j < 8; ++j) {
                        float f = (float)v[j];
                        f = fmaxf(fmaf(f, scale[g * 8 + j], shift[g * 8 + j]), 0.f);
                        h[j] = (f16)f;
                    }
                } else h = v;
            } else {
                const float* X = (const float*)Xv;
                float4 a = *(const float4*)(X + (size_t)grow * HC + g * 8);
                float4 c = *(const float4*)(X + (size_t)grow * HC + g * 8 + 4);
                h[0] = (f16)a.x; h[1] = (f16)a.y; h[2] = (f16)a.z; h[3] = (f16)a.w;
                h[4] = (f16)c.x; h[5] = (f16)c.y; h[6] = (f16)c.z; h[7] = (f16)c.w;
            }
        }
        *(f16x8*)&Ah[r][g * 8] = h;
    }
    __syncthreads();

    const int wv   = tid >> 6;
    const int lane = tid & 63;
    const int m    = lane & 15;
    const int kq   = (lane >> 4) * 8;

    f32x4 acc[8] = {};
#pragma unroll
    for (int kc = 0; kc < HC; kc += 32) {
        f16x8 a = *(const f16x8*)&Ah[wv * 16 + m][kc + kq];
#pragma unroll
        for (int t = 0; t < 8; ++t) {
            f16x8 b = *(const f16x8*)&Bh[t * 16 + m][kc + kq];
            acc[t] = __builtin_amdgcn_mfma_f32_16x16x32_f16(a, b, acc[t], 0, 0, 0);
        }
    }

    const int rbase = row0 + wv * 16 + (lane >> 4) * 4;
#pragma unroll
    for (int t = 0; t < 8; ++t) {
#pragma unroll
        for (int r = 0; r < 4; ++r) {
            int grow = rbase + r;
            if (grow < n)
                Y[(size_t)grow * HC + t * 16 + m] = (f16)acc[t][r];
        }
    }
}

// ---------------- CSR gather agg: 4 edges/wave-iter, 16B/lane ---------------
// out[v] = dis[v]*(sum_e dis[s]*xw[s] + dis[v]*xw[v]) + b ; fused BN stats.
__global__ __launch_bounds__(256) void gcn_agg_f16(const f16* __restrict__ xw,
                                                   const int* __restrict__ srcs,
                                                   const int* __restrict__ rowptr,
                                                   const float* __restrict__ dis,
                                                   const float* __restrict__ bias,
                                                   f16* __restrict__ out,
                                                   float* __restrict__ stats,
                                                   int n, int nwaves) {
    __shared__ float lds_s[4][128], lds_q[4][128];
    const int wv   = threadIdx.x >> 6;
    const int lane = threadIdx.x & 63;
    const int g    = lane >> 4;      // edge subgroup 0..3
    const int cg   = lane & 15;      // channel group (8 channels)

    float b8[8];
#pragma unroll
    for (int j = 0; j < 8; ++j) b8[j] = bias[cg * 8 + j];

    float s8[8] = {}, q8[8] = {};

    for (int node = blockIdx.x * 4 + wv; node < n; node += nwaves) {
        const int e0 = rowptr[node];
        const int e1 = rowptr[node + 1];
        float acc[8] = {};
        for (int e = e0; e < e1; e += 4) {
            int idx = e + g;
            bool valid = idx < e1;
            int sidx = srcs[valid ? idx : e0];
            float w = valid ? dis[sidx] : 0.f;
            f16x8 v = *(const f16x8*)(xw + (size_t)sidx * HC + cg * 8);
#pragma unroll
            for (int j = 0; j < 8; ++j)
                acc[j] = fmaf((float)v[j], w, acc[j]);
        }
#pragma unroll
        for (int j = 0; j < 8; ++j) acc[j] += __shfl_xor(acc[j], 16);
#pragma unroll
        for (int j = 0; j < 8; ++j) acc[j] += __shfl_xor(acc[j], 32);

        if (g == 0) {
            float dv = dis[node];
            f16x8 self = *(const f16x8*)(xw + (size_t)node * HC + cg * 8);
            f16x8 o;
#pragma unroll
            for (int j = 0; j < 8; ++j) {
                float r = fmaf(acc[j] + (float)self[j] * dv, dv, b8[j]);
                o[j] = (f16)r;
                s8[j] += r;
                q8[j] += r * r;
            }
            *(f16x8*)(out + (size_t)node * HC + cg * 8) = o;
        }
    }

    if (g == 0) {
#pragma unroll
        for (int j = 0; j < 8; ++j) {
            lds_s[wv][cg * 8 + j] = s8[j];
            lds_q[wv][cg * 8 + j] = q8[j];
        }
    }
    __syncthreads();
    float* stripe = stats + (size_t)(blockIdx.x & (NSTRIPE - 1)) * 256;
    if (threadIdx.x < 128) {
        float s = lds_s[0][threadIdx.x] + lds_s[1][threadIdx.x] +
                  lds_s[2][threadIdx.x] + lds_s[3][threadIdx.x];
        float q = lds_q[0][threadIdx.x] + lds_q[1][threadIdx.x] +
                  lds_q[2][threadIdx.x] + lds_q[3][threadIdx.x];
        atomicAdd(&stripe[threadIdx.x], s);
        atomicAdd(&stripe[128 + threadIdx.x], q);
    }
}

__global__ void bn_finalize(const float* __restrict__ stats,
                            const float* __restrict__ g, const float* __restrict__ be,
                            float* __restrict__ scale, float* __restrict__ shift, int n) {
    int c = threadIdx.x;
    float s = 0.f, q = 0.f;
    for (int t = 0; t < NSTRIPE; ++t) {
        s += stats[t * 256 + c];
        q += stats[t * 256 + 128 + c];
    }
    float m = s / (float)n;
    float v = q / (float)n - m * m;
    float sc = g[c] * rsqrtf(fmaxf(v, 0.f) + EPS_BN);
    scale[c] = sc;
    shift[c] = be[c] - m * sc;
}

// ---------------- MLP head, tiled GEMM (fp16 input, BN2+ReLU fused) ---------
__global__ __launch_bounds__(256) void mlp_gemm(const f16* __restrict__ h,
                                                const float* __restrict__ scale,
                                                const float* __restrict__ shift,
                                                const float* __restrict__ Wm1,
                                                const float* __restrict__ bm1,
                                                const float* __restrict__ Wm2,
                                                const float* __restrict__ bm2,
                                                float* __restrict__ out, int n) {
    __shared__ float hs[64][HC + 4];
    __shared__ float red[64][17];
    const int tid  = threadIdx.x;
    const int row0 = blockIdx.x * 64;

    for (int i = tid; i < 1024; i += 256) {
        int r = i >> 4, g = i & 15;
        float4 lo = make_float4(0.f, 0.f, 0.f, 0.f);
        float4 hi = make_float4(0.f, 0.f, 0.f, 0.f);
        if (row0 + r < n) {
            f16x8 v = *(const f16x8*)(h + (size_t)(row0 + r) * HC + g * 8);
            float4 sa = *(const float4*)(scale + g * 8);
            float4 sb = *(const float4*)(scale + g * 8 + 4);
            float4 ha = *(const float4*)(shift + g * 8);
            float4 hb = *(const float4*)(shift + g * 8 + 4);
            lo.x = fmaxf(fmaf((float)v[0], sa.x, ha.x), 0.f);
            lo.y = fmaxf(fmaf((float)v[1], sa.y, ha.y), 0.f);
            lo.z = fmaxf(fmaf((float)v[2], sa.z, ha.z), 0.f);
            lo.w = fmaxf(fmaf((float)v[3], sa.w, ha.w), 0.f);
            hi.x = fmaxf(fmaf((float)v[4], sb.x, hb.x), 0.f);
            hi.y = fmaxf(fmaf((float)v[5], sb.y, hb.y), 0.f);
            hi.z = fmaxf(fmaf((float)v[6], sb.z, hb.z), 0.f);
            hi.w = fmaxf(fmaf((float)v[7], sb.w, hb.w), 0.f);
        }
        *(float4*)&hs[r][g * 8]     = lo;
        *(float4*)&hs[r][g * 8 + 4] = hi;
    }
    __syncthreads();

    const int cg = tid & 15;
    const int rg = tid >> 4;
    const int c0 = cg * 4;
    const int r0 = rg * 4;

    float acc[4][4];
#pragma unroll
    for (int i = 0; i < 4; ++i)
#pragma unroll
        for (int j = 0; j < 4; ++j) acc[i][j] = 0.f;

    for (int kk = 0; kk < HC; kk += 4) {
        float xv[4][4];
        *(float4*)xv[0] = *(const float4*)&hs[r0 + 0][kk];
        *(float4*)xv[1] = *(const float4*)&hs[r0 + 1][kk];
        *(float4*)xv[2] = *(const float4*)&hs[r0 + 2][kk];
        *(float4*)xv[3] = *(const float4*)&hs[r0 + 3][kk];
#pragma unroll
        for (int j = 0; j < 4; ++j) {
            float wv[4];
            *(float4*)wv = *(const float4*)(Wm1 + (size_t)(kk + j) * 64 + c0);
#pragma unroll
            for (int i = 0; i < 4; ++i)
#pragma unroll
                for (int c = 0; c < 4; ++c)
                    acc[i][c] = fmaf(xv[i][j], wv[c], acc[i][c]);
        }
    }

    float4 b1v = *(const float4*)(bm1 + c0);
    float4 w2v = *(const float4*)(Wm2 + c0);
#pragma unroll
    for (int i = 0; i < 4; ++i) {
        float t0 = fmaxf(acc[i][0] + b1v.x, 0.f) * w2v.x;
        float t1 = fmaxf(acc[i][1] + b1v.y, 0.f) * w2v.y;
        float t2 = fmaxf(acc[i][2] + b1v.z, 0.f) * w2v.z;
        float t3 = fmaxf(acc[i][3] + b1v.w, 0.f) * w2v.w;
        red[r0 + i][cg] = (t0 + t1) + (t2 + t3);
    }
    __syncthreads();

    if (tid < 64 && row0 + tid < n) {
        float s = 0.f;
#pragma unroll
        for (int g = 0; g < 16; ++g) s += red[tid][g];
        out[row0 + tid] = s + bm2[0];
    }
}

extern "C" void kernel_launch(void* const* d_in, const int* in_sizes, int n_in,
                              void* d_out, int out_size, void* d_ws, size_t ws_size,
                              hipStream_t stream) {
    const float* x   = (const float*)d_in[0];
    const int*   ei  = (const int*)  d_in[1];
    const float* W1  = (const float*)d_in[2];
    const float* b1  = (const float*)d_in[3];
    const float* g1  = (const float*)d_in[4];
    const float* be1 = (const float*)d_in[5];
    const float* W2  = (const float*)d_in[6];
    const float* b2  = (const float*)d_in[7];
    const float* g2  = (const float*)d_in[8];
    const float* be2 = (const float*)d_in[9];
    const float* Wm1 = (const float*)d_in[10];
    const float* bm1 = (const float*)d_in[11];
    const float* Wm2 = (const float*)d_in[12];
    const float* bm2 = (const float*)d_in[13];
    float* out = (float*)d_out;

    const int n = in_sizes[0] / HC;       // 100000
    const int E = in_sizes[1] / 2;        // 1600000
    const int* srcp = ei;
    const int* dstp = ei + E;
    const int nb = (n + BNODES - 1) >> BSHIFT;   // buckets

    char* ws = (char*)d_ws;
    size_t off = 0;
    auto alloc = [&](size_t bytes) { void* p = ws + off; off = (off + bytes + 511) & ~511ULL; return p; };
    float*  dis    = (float*) alloc((size_t)n * 4);
    int*    degi   = (int*)   alloc((size_t)n * 4);
    int*    excl   = (int*)   alloc((size_t)n * 4);
    int*    rowptr = (int*)   alloc((size_t)(n + 1) * 4);
    int*    bsums  = (int*)   alloc(4096);
    int*    cur1   = (int*)   alloc((size_t)nb * 4);
    int2*   bucketed = (int2*)alloc((size_t)E * 8);
    int*    srcs   = (int*)   alloc((size_t)E * 4);
    f16*    xwh    = (f16*)   alloc((size_t)n * HC * 2);
    f16*    bufBh  = (f16*)   alloc((size_t)n * HC * 2);
    f16*    Wt1    = (f16*)   alloc((size_t)HC * HC * 2);
    f16*    Wt2    = (f16*)   alloc((size_t)HC * HC * 2);
    float*  stats  = (float*) alloc(NSTRIPE * 256 * 4);
    float*  scale1 = (float*) alloc(1024);
    float*  shift1 = scale1 + 128;
    float*  scale2 = (float*) alloc(1024);
    float*  shift2 = scale2 + 128;

    const int gemmBlocks  = (n + 63) / 64;
    const int nScanBlocks = (n + 1023) / 1024;
    const int aggWaves    = AGG_BLOCKS * 4;

    // ---- CSR build (shared by both layers) ----
    hipMemsetAsync(degi, 0, (size_t)n * 4, stream);
    degi_kernel<<<(E + 255) / 256, 256, 0, stream>>>(dstp, degi, E);
    dis_kernel<<<(n + 255) / 256, 256, 0, stream>>>(degi, dis, n);
    scan1<<<nScanBlocks, 256, 0, stream>>>(degi, excl, bsums, n);
    scan2<<<1, 64, 0, stream>>>(bsums, nScanBlocks);
    scan3<<<(n + 256) / 256, 256, 0, stream>>>(excl, bsums, rowptr, n, E);
    binit<<<(nb + 255) / 256, 256, 0, stream>>>(rowptr, cur1, nb, n);
    edge_bucket<<<(E + 255) / 256, 256, 0, stream>>>(srcp, dstp, cur1, bucketed, E);
    edge_sort<<<nb, 256, 0, stream>>>(bucketed, rowptr, srcs, n);

    // ---- weight prep ----
    wprep<<<64, 256, 0, stream>>>(W1, Wt1);
    wprep<<<64, 256, 0, stream>>>(W2, Wt2);

    // ---- layer 1 ----
    gemm_mfma<0, 0><<<gemmBlocks, 256, 0, stream>>>(x, Wt1, nullptr, nullptr, xwh, n);
    hipMemsetAsync(stats, 0, NSTRIPE * 256 * 4, stream);
    gcn_agg_f16<<<AGG_BLOCKS, 256, 0, stream>>>(xwh, srcs, rowptr, dis, b1,
                                                bufBh, stats, n, aggWaves);
    bn_finalize<<<1, 128, 0, stream>>>(stats, g1, be1, scale1, shift1, n);

    // ---- layer 2 (BN1+ReLU fused into GEMM staging) ----
    gemm_mfma<1, 1><<<gemmBlocks, 256, 0, stream>>>(bufBh, Wt2, scale1, shift1, xwh, n);
    hipMemsetAsync(stats, 0, NSTRIPE * 256 * 4, stream);
    gcn_agg_f16<<<AGG_BLOCKS, 256, 0, stream>>>(xwh, srcs, rowptr, dis, b2,
                                                bufBh, stats, n, aggWaves);
    bn_finalize<<<1, 128, 0, stream>>>(stats, g2, be2, scale2, shift2, n);

    // ---- MLP head (BN2+ReLU fused) ----
    mlp_gemm<<<gemmBlocks, 256, 0, stream>>>(bufBh, scale2, shift2, Wm1, bm1, Wm2, bm2, out, n);
}

// Round 8
// 472.822 us; speedup vs baseline: 1.7389x; 1.7389x over previous
//
#include <hip/hip_runtime.h>
#include <hip/hip_fp16.h>

#define HC 128
#define EPS_BN 1e-5f
#define NSTRIPE 8
#define AGG_BLOCKS 3072
#define BSHIFT 9                 // 512 nodes per bucket
#define BNODES (1 << BSHIFT)
#define CHUNK 8192               // edges per pass-1 block
#define SRC_BITS 18              // src < 2^18

typedef _Float16 f16;
typedef f16  f16x8 __attribute__((ext_vector_type(8)));
typedef float f32x4 __attribute__((ext_vector_type(4)));

// ---------------- degree count (int) ----------------
__global__ void degi_kernel(const int* __restrict__ dst, int* __restrict__ degi, int E) {
    int e = blockIdx.x * 256 + threadIdx.x;
    if (e < E) atomicAdd(&degi[dst[e]], 1);
}

__global__ void dis_kernel(const int* __restrict__ degi, float* __restrict__ dis, int n) {
    int i = blockIdx.x * 256 + threadIdx.x;
    if (i < n) dis[i] = rsqrtf((float)degi[i] + 1.0f);  // +1 self-loop
}

// ---------------- exclusive scan of degi -> rowptr ----------------
__global__ __launch_bounds__(256) void scan1(const int* __restrict__ degi, int* __restrict__ excl,
                                             int* __restrict__ bsums, int n) {
    __shared__ int ts[256];
    const int tid = threadIdx.x;
    const int base = blockIdx.x * 1024 + tid * 4;
    int v0 = 0, v1 = 0, v2 = 0, v3 = 0;
    if (base + 3 < n) {
        int4 v = *(const int4*)(degi + base);
        v0 = v.x; v1 = v.y; v2 = v.z; v3 = v.w;
    } else {
        if (base + 0 < n) v0 = degi[base + 0];
        if (base + 1 < n) v1 = degi[base + 1];
        if (base + 2 < n) v2 = degi[base + 2];
        if (base + 3 < n) v3 = degi[base + 3];
    }
    int p1 = v0, p2 = v0 + v1, p3 = v0 + v1 + v2, total = p3 + v3;
    ts[tid] = total;
    __syncthreads();
    for (int off = 1; off < 256; off <<= 1) {
        int t = (tid >= off) ? ts[tid - off] : 0;
        __syncthreads();
        ts[tid] += t;
        __syncthreads();
    }
    int eb = (tid ? ts[tid - 1] : 0);
    if (tid == 255) bsums[blockIdx.x] = ts[255];
    if (base + 0 < n) excl[base + 0] = eb;
    if (base + 1 < n) excl[base + 1] = eb + p1;
    if (base + 2 < n) excl[base + 2] = eb + p2;
    if (base + 3 < n) excl[base + 3] = eb + p3;
}

__global__ void scan2(int* __restrict__ bsums, int nb) {
    if (threadIdx.x == 0) {
        int s = 0;
        for (int i = 0; i < nb; ++i) { int t = bsums[i]; bsums[i] = s; s += t; }
    }
}

__global__ void scan3(const int* __restrict__ excl, const int* __restrict__ bsums,
                      int* __restrict__ rowptr, int n, int E) {
    int i = blockIdx.x * 256 + threadIdx.x;
    if (i < n) rowptr[i] = excl[i] + bsums[i >> 10];
    if (i == n) rowptr[n] = E;
}

// ---------------- bucket cursor init from rowptr ----------------------------
__global__ void binit(const int* __restrict__ rowptr, int* __restrict__ gcur, int nb, int n) {
    int b = blockIdx.x * 256 + threadIdx.x;
    if (b < nb) {
        int node0 = b << BSHIFT;
        gcur[b] = rowptr[node0 < n ? node0 : n];
    }
}

// ---------------- pass 1: block-private bucket runs -------------------------
// Each block: count chunk's edges per bucket (LDS) -> reserve contiguous runs
// (one global atomic per bucket) -> place packed (dstLocal<<18 | src) in runs.
__global__ __launch_bounds__(256) void edge_bin(const int* __restrict__ src,
                                                const int* __restrict__ dst,
                                                int* __restrict__ gcur,
                                                unsigned int* __restrict__ packed, int E) {
    __shared__ int cnt[256];
    __shared__ int cur[256];
    const int tid = threadIdx.x;
    const int e0 = blockIdx.x * CHUNK;
    cnt[tid] = 0;
    __syncthreads();
    for (int i = tid; i < CHUNK; i += 256) {
        int e = e0 + i;
        if (e < E) atomicAdd(&cnt[dst[e] >> BSHIFT], 1);
    }
    __syncthreads();
    cur[tid] = (cnt[tid] > 0) ? atomicAdd(&gcur[tid], cnt[tid]) : 0;
    __syncthreads();
    for (int i = tid; i < CHUNK; i += 256) {
        int e = e0 + i;
        if (e < E) {
            int s = src[e], d = dst[e];
            int pos = atomicAdd(&cur[d >> BSHIFT], 1);
            packed[pos] = ((unsigned)(d & (BNODES - 1)) << SRC_BITS) | (unsigned)s;
        }
    }
}

// ---------------- pass 2: within-bucket exact CSR placement -----------------
__global__ __launch_bounds__(256) void edge_sort(const unsigned int* __restrict__ packed,
                                                 const int* __restrict__ rowptr,
                                                 int* __restrict__ srcs, int n) {
    __shared__ int cur[BNODES];
    const int node0 = blockIdx.x << BSHIFT;
    const int tid = threadIdx.x;
    for (int t = tid; t < BNODES; t += 256) {
        int node = node0 + t;
        if (node < n) cur[t] = rowptr[node];
    }
    __syncthreads();
    const int e0 = rowptr[node0];
    const int e1 = rowptr[min(node0 + BNODES, n)];
    for (int e = e0 + tid; e < e1; e += 256) {
        unsigned p = packed[e];
        int pos = atomicAdd(&cur[p >> SRC_BITS], 1);
        srcs[pos] = (int)(p & ((1u << SRC_BITS) - 1));
    }
}

// ---------------- W transpose + fp16 convert: Wt[c][k] = W[k][c] ------------
__global__ void wprep(const float* __restrict__ W, f16* __restrict__ Wt) {
    int idx = blockIdx.x * 256 + threadIdx.x;   // 16384 total
    if (idx < HC * HC) {
        int k = idx >> 7, c = idx & 127;
        Wt[(size_t)c * HC + k] = (f16)W[idx];
    }
}

// ---------------- MFMA GEMM: Y[n,128](f16) = T(X)[n,128] @ W[128,128] -------
template<int SRC_F16, int TRANS>
__global__ __launch_bounds__(256) void gemm_mfma(const void* __restrict__ Xv,
                                                 const f16* __restrict__ Wt,
                                                 const float* __restrict__ scale,
                                                 const float* __restrict__ shift,
                                                 f16* __restrict__ Y, int n) {
    __shared__ f16 Ah[64][136];
    __shared__ f16 Bh[128][136];
    const int tid  = threadIdx.x;
    const int row0 = blockIdx.x * 64;

#pragma unroll
    for (int i = 0; i < 8; ++i) {
        int idx = i * 256 + tid;
        int r = idx >> 4, g = idx & 15;
        *(f16x8*)&Bh[r][g * 8] = *(const f16x8*)(Wt + (size_t)r * HC + g * 8);
    }
#pragma unroll
    for (int i = 0; i < 4; ++i) {
        int idx = i * 256 + tid;
        int r = idx >> 4, g = idx & 15;
        int grow = row0 + r;
        f16x8 h = {};
        if (grow < n) {
            if constexpr (SRC_F16) {
                f16x8 v = *(const f16x8*)((const f16*)Xv + (size_t)grow * HC + g * 8);
                if constexpr (TRANS) {
#pragma unroll
                    for (int j = 0; j < 8; ++j) {
                        float f = (float)v[j];
                        f = fmaxf(fmaf(f, scale[g * 8 + j], shift[g * 8 + j]), 0.f);
                        h[j] = (f16)f;
                    }
                } else h = v;
            } else {
                const float* X = (const float*)Xv;
                float4 a = *(const float4*)(X + (size_t)grow * HC + g * 8);
                float4 c = *(const float4*)(X + (size_t)grow * HC + g * 8 + 4);
                h[0] = (f16)a.x; h[1] = (f16)a.y; h[2] = (f16)a.z; h[3] = (f16)a.w;
                h[4] = (f16)c.x; h[5] = (f16)c.y; h[6] = (f16)c.z; h[7] = (f16)c.w;
            }
        }
        *(f16x8*)&Ah[r][g * 8] = h;
    }
    __syncthreads();

    const int wv   = tid >> 6;
    const int lane = tid & 63;
    const int m    = lane & 15;
    const int kq   = (lane >> 4) * 8;

    f32x4 acc[8] = {};
#pragma unroll
    for (int kc = 0; kc < HC; kc += 32) {
        f16x8 a = *(const f16x8*)&Ah[wv * 16 + m][kc + kq];
#pragma unroll
        for (int t = 0; t < 8; ++t) {
            f16x8 b = *(const f16x8*)&Bh[t * 16 + m][kc + kq];
            acc[t] = __builtin_amdgcn_mfma_f32_16x16x32_f16(a, b, acc[t], 0, 0, 0);
        }
    }

    const int rbase = row0 + wv * 16 + (lane >> 4) * 4;
#pragma unroll
    for (int t = 0; t < 8; ++t) {
#pragma unroll
        for (int r = 0; r < 4; ++r) {
            int grow = rbase + r;
            if (grow < n)
                Y[(size_t)grow * HC + t * 16 + m] = (f16)acc[t][r];
        }
    }
}

// ---------------- CSR gather agg: 4 edges/wave-iter, 16B/lane ---------------
// out[v] = dis[v]*(sum_e dis[s]*xw[s] + dis[v]*xw[v]) + b ; fused BN stats.
__global__ __launch_bounds__(256) void gcn_agg_f16(const f16* __restrict__ xw,
                                                   const int* __restrict__ srcs,
                                                   const int* __restrict__ rowptr,
                                                   const float* __restrict__ dis,
                                                   const float* __restrict__ bias,
                                                   f16* __restrict__ out,
                                                   float* __restrict__ stats,
                                                   int n, int nwaves) {
    __shared__ float lds_s[4][128], lds_q[4][128];
    const int wv   = threadIdx.x >> 6;
    const int lane = threadIdx.x & 63;
    const int g    = lane >> 4;      // edge subgroup 0..3
    const int cg   = lane & 15;      // channel group (8 channels)

    float b8[8];
#pragma unroll
    for (int j = 0; j < 8; ++j) b8[j] = bias[cg * 8 + j];

    float s8[8] = {}, q8[8] = {};

    for (int node = blockIdx.x * 4 + wv; node < n; node += nwaves) {
        const int e0 = rowptr[node];
        const int e1 = rowptr[node + 1];
        float acc[8] = {};
        for (int e = e0; e < e1; e += 4) {
            int idx = e + g;
            bool valid = idx < e1;
            int sidx = srcs[valid ? idx : e0];
            float w = valid ? dis[sidx] : 0.f;
            f16x8 v = *(const f16x8*)(xw + (size_t)sidx * HC + cg * 8);
#pragma unroll
            for (int j = 0; j < 8; ++j)
                acc[j] = fmaf((float)v[j], w, acc[j]);
        }
#pragma unroll
        for (int j = 0; j < 8; ++j) acc[j] += __shfl_xor(acc[j], 16);
#pragma unroll
        for (int j = 0; j < 8; ++j) acc[j] += __shfl_xor(acc[j], 32);

        if (g == 0) {
            float dv = dis[node];
            f16x8 self = *(const f16x8*)(xw + (size_t)node * HC + cg * 8);
            f16x8 o;
#pragma unroll
            for (int j = 0; j < 8; ++j) {
                float r = fmaf(acc[j] + (float)self[j] * dv, dv, b8[j]);
                o[j] = (f16)r;
                s8[j] += r;
                q8[j] += r * r;
            }
            *(f16x8*)(out + (size_t)node * HC + cg * 8) = o;
        }
    }

    if (g == 0) {
#pragma unroll
        for (int j = 0; j < 8; ++j) {
            lds_s[wv][cg * 8 + j] = s8[j];
            lds_q[wv][cg * 8 + j] = q8[j];
        }
    }
    __syncthreads();
    float* stripe = stats + (size_t)(blockIdx.x & (NSTRIPE - 1)) * 256;
    if (threadIdx.x < 128) {
        float s = lds_s[0][threadIdx.x] + lds_s[1][threadIdx.x] +
                  lds_s[2][threadIdx.x] + lds_s[3][threadIdx.x];
        float q = lds_q[0][threadIdx.x] + lds_q[1][threadIdx.x] +
                  lds_q[2][threadIdx.x] + lds_q[3][threadIdx.x];
        atomicAdd(&stripe[threadIdx.x], s);
        atomicAdd(&stripe[128 + threadIdx.x], q);
    }
}

__global__ void bn_finalize(const float* __restrict__ stats,
                            const float* __restrict__ g, const float* __restrict__ be,
                            float* __restrict__ scale, float* __restrict__ shift, int n) {
    int c = threadIdx.x;
    float s = 0.f, q = 0.f;
    for (int t = 0; t < NSTRIPE; ++t) {
        s += stats[t * 256 + c];
        q += stats[t * 256 + 128 + c];
    }
    float m = s / (float)n;
    float v = q / (float)n - m * m;
    float sc = g[c] * rsqrtf(fmaxf(v, 0.f) + EPS_BN);
    scale[c] = sc;
    shift[c] = be[c] - m * sc;
}

// ---------------- MLP head, tiled GEMM (fp16 input, BN2+ReLU fused) ---------
__global__ __launch_bounds__(256) void mlp_gemm(const f16* __restrict__ h,
                                                const float* __restrict__ scale,
                                                const float* __restrict__ shift,
                                                const float* __restrict__ Wm1,
                                                const float* __restrict__ bm1,
                                                const float* __restrict__ Wm2,
                                                const float* __restrict__ bm2,
                                                float* __restrict__ out, int n) {
    __shared__ float hs[64][HC + 4];
    __shared__ float red[64][17];
    const int tid  = threadIdx.x;
    const int row0 = blockIdx.x * 64;

    for (int i = tid; i < 1024; i += 256) {
        int r = i >> 4, g = i & 15;
        float4 lo = make_float4(0.f, 0.f, 0.f, 0.f);
        float4 hi = make_float4(0.f, 0.f, 0.f, 0.f);
        if (row0 + r < n) {
            f16x8 v = *(const f16x8*)(h + (size_t)(row0 + r) * HC + g * 8);
            float4 sa = *(const float4*)(scale + g * 8);
            float4 sb = *(const float4*)(scale + g * 8 + 4);
            float4 ha = *(const float4*)(shift + g * 8);
            float4 hb = *(const float4*)(shift + g * 8 + 4);
            lo.x = fmaxf(fmaf((float)v[0], sa.x, ha.x), 0.f);
            lo.y = fmaxf(fmaf((float)v[1], sa.y, ha.y), 0.f);
            lo.z = fmaxf(fmaf((float)v[2], sa.z, ha.z), 0.f);
            lo.w = fmaxf(fmaf((float)v[3], sa.w, ha.w), 0.f);
            hi.x = fmaxf(fmaf((float)v[4], sb.x, hb.x), 0.f);
            hi.y = fmaxf(fmaf((float)v[5], sb.y, hb.y), 0.f);
            hi.z = fmaxf(fmaf((float)v[6], sb.z, hb.z), 0.f);
            hi.w = fmaxf(fmaf((float)v[7], sb.w, hb.w), 0.f);
        }
        *(float4*)&hs[r][g * 8]     = lo;
        *(float4*)&hs[r][g * 8 + 4] = hi;
    }
    __syncthreads();

    const int cg = tid & 15;
    const int rg = tid >> 4;
    const int c0 = cg * 4;
    const int r0 = rg * 4;

    float acc[4][4];
#pragma unroll
    for (int i = 0; i < 4; ++i)
#pragma unroll
        for (int j = 0; j < 4; ++j) acc[i][j] = 0.f;

    for (int kk = 0; kk < HC; kk += 4) {
        float xv[4][4];
        *(float4*)xv[0] = *(const float4*)&hs[r0 + 0][kk];
        *(float4*)xv[1] = *(const float4*)&hs[r0 + 1][kk];
        *(float4*)xv[2] = *(const float4*)&hs[r0 + 2][kk];
        *(float4*)xv[3] = *(const float4*)&hs[r0 + 3][kk];
#pragma unroll
        for (int j = 0; j < 4; ++j) {
            float wv[4];
            *(float4*)wv = *(const float4*)(Wm1 + (size_t)(kk + j) * 64 + c0);
#pragma unroll
            for (int i = 0; i < 4; ++i)
#pragma unroll
                for (int c = 0; c < 4; ++c)
                    acc[i][c] = fmaf(xv[i][j], wv[c], acc[i][c]);
        }
    }

    float4 b1v = *(const float4*)(bm1 + c0);
    float4 w2v = *(const float4*)(Wm2 + c0);
#pragma unroll
    for (int i = 0; i < 4; ++i) {
        float t0 = fmaxf(acc[i][0] + b1v.x, 0.f) * w2v.x;
        float t1 = fmaxf(acc[i][1] + b1v.y, 0.f) * w2v.y;
        float t2 = fmaxf(acc[i][2] + b1v.z, 0.f) * w2v.z;
        float t3 = fmaxf(acc[i][3] + b1v.w, 0.f) * w2v.w;
        red[r0 + i][cg] = (t0 + t1) + (t2 + t3);
    }
    __syncthreads();

    if (tid < 64 && row0 + tid < n) {
        float s = 0.f;
#pragma unroll
        for (int g = 0; g < 16; ++g) s += red[tid][g];
        out[row0 + tid] = s + bm2[0];
    }
}

extern "C" void kernel_launch(void* const* d_in, const int* in_sizes, int n_in,
                              void* d_out, int out_size, void* d_ws, size_t ws_size,
                              hipStream_t stream) {
    const float* x   = (const float*)d_in[0];
    const int*   ei  = (const int*)  d_in[1];
    const float* W1  = (const float*)d_in[2];
    const float* b1  = (const float*)d_in[3];
    const float* g1  = (const float*)d_in[4];
    const float* be1 = (const float*)d_in[5];
    const float* W2  = (const float*)d_in[6];
    const float* b2  = (const float*)d_in[7];
    const float* g2  = (const float*)d_in[8];
    const float* be2 = (const float*)d_in[9];
    const float* Wm1 = (const float*)d_in[10];
    const float* bm1 = (const float*)d_in[11];
    const float* Wm2 = (const float*)d_in[12];
    const float* bm2 = (const float*)d_in[13];
    float* out = (float*)d_out;

    const int n = in_sizes[0] / HC;       // 100000
    const int E = in_sizes[1] / 2;        // 1600000
    const int* srcp = ei;
    const int* dstp = ei + E;
    const int nb = (n + BNODES - 1) >> BSHIFT;   // 196 buckets

    char* ws = (char*)d_ws;
    size_t off = 0;
    auto alloc = [&](size_t bytes) { void* p = ws + off; off = (off + bytes + 511) & ~511ULL; return p; };
    float*  dis    = (float*) alloc((size_t)n * 4);
    int*    degi   = (int*)   alloc((size_t)n * 4);
    int*    excl   = (int*)   alloc((size_t)n * 4);
    int*    rowptr = (int*)   alloc((size_t)(n + 1) * 4);
    int*    bsums  = (int*)   alloc(4096);
    int*    gcur   = (int*)   alloc(1024);
    unsigned int* packed = (unsigned int*)alloc((size_t)E * 4);
    int*    srcs   = (int*)   alloc((size_t)E * 4);
    f16*    xwh    = (f16*)   alloc((size_t)n * HC * 2);
    f16*    bufBh  = (f16*)   alloc((size_t)n * HC * 2);
    f16*    Wt1    = (f16*)   alloc((size_t)HC * HC * 2);
    f16*    Wt2    = (f16*)   alloc((size_t)HC * HC * 2);
    float*  stats  = (float*) alloc(NSTRIPE * 256 * 4);
    float*  scale1 = (float*) alloc(1024);
    float*  shift1 = scale1 + 128;
    float*  scale2 = (float*) alloc(1024);
    float*  shift2 = scale2 + 128;

    const int gemmBlocks  = (n + 63) / 64;
    const int nScanBlocks = (n + 1023) / 1024;
    const int binBlocks   = (E + CHUNK - 1) / CHUNK;
    const int aggWaves    = AGG_BLOCKS * 4;

    // ---- CSR build (shared by both layers) ----
    hipMemsetAsync(degi, 0, (size_t)n * 4, stream);
    degi_kernel<<<(E + 255) / 256, 256, 0, stream>>>(dstp, degi, E);
    dis_kernel<<<(n + 255) / 256, 256, 0, stream>>>(degi, dis, n);
    scan1<<<nScanBlocks, 256, 0, stream>>>(degi, excl, bsums, n);
    scan2<<<1, 64, 0, stream>>>(bsums, nScanBlocks);
    scan3<<<(n + 256) / 256, 256, 0, stream>>>(excl, bsums, rowptr, n, E);
    binit<<<1, 256, 0, stream>>>(rowptr, gcur, nb, n);
    edge_bin<<<binBlocks, 256, 0, stream>>>(srcp, dstp, gcur, packed, E);
    edge_sort<<<nb, 256, 0, stream>>>(packed, rowptr, srcs, n);

    // ---- weight prep ----
    wprep<<<64, 256, 0, stream>>>(W1, Wt1);
    wprep<<<64, 256, 0, stream>>>(W2, Wt2);

    // ---- layer 1 ----
    gemm_mfma<0, 0><<<gemmBlocks, 256, 0, stream>>>(x, Wt1, nullptr, nullptr, xwh, n);
    hipMemsetAsync(stats, 0, NSTRIPE * 256 * 4, stream);
    gcn_agg_f16<<<AGG_BLOCKS, 256, 0, stream>>>(xwh, srcs, rowptr, dis, b1,
                                                bufBh, stats, n, aggWaves);
    bn_finalize<<<1, 128, 0, stream>>>(stats, g1, be1, scale1, shift1, n);

    // ---- layer 2 (BN1+ReLU fused into GEMM staging) ----
    gemm_mfma<1, 1><<<gemmBlocks, 256, 0, stream>>>(bufBh, Wt2, scale1, shift1, xwh, n);
    hipMemsetAsync(stats, 0, NSTRIPE * 256 * 4, stream);
    gcn_agg_f16<<<AGG_BLOCKS, 256, 0, stream>>>(xwh, srcs, rowptr, dis, b2,
                                                bufBh, stats, n, aggWaves);
    bn_finalize<<<1, 128, 0, stream>>>(stats, g2, be2, scale2, shift2, n);

    // ---- MLP head (BN2+ReLU fused) ----
    mlp_gemm<<<gemmBlocks, 256, 0, stream>>>(bufBh, scale2, shift2, Wm1, bm1, Wm2, bm2, out, n);
}

// Round 9
// 419.949 us; speedup vs baseline: 1.9579x; 1.1259x over previous
//
#include <hip/hip_runtime.h>
#include <hip/hip_fp16.h>

#define HC 128
#define EPS_BN 1e-5f
#define NSTRIPE 8
#define AGG_BLOCKS 3072
#define BSHIFT 9                 // 512 nodes per bucket
#define BNODES (1 << BSHIFT)
#define CHUNK 8192               // edges per pass-1 block
#define SRC_BITS 18              // src < 2^18

typedef _Float16 f16;
typedef f16  f16x8 __attribute__((ext_vector_type(8)));
typedef float f32x4 __attribute__((ext_vector_type(4)));

// ---------------- degree count (int) ----------------
__global__ void degi_kernel(const int* __restrict__ dst, int* __restrict__ degi, int E) {
    int e = blockIdx.x * 256 + threadIdx.x;
    if (e < E) atomicAdd(&degi[dst[e]], 1);
}

__global__ void dis_kernel(const int* __restrict__ degi, float* __restrict__ dis, int n) {
    int i = blockIdx.x * 256 + threadIdx.x;
    if (i < n) dis[i] = rsqrtf((float)degi[i] + 1.0f);  // +1 self-loop
}

// ---------------- exclusive scan of degi -> rowptr ----------------
__global__ __launch_bounds__(256) void scan1(const int* __restrict__ degi, int* __restrict__ excl,
                                             int* __restrict__ bsums, int n) {
    __shared__ int ts[256];
    const int tid = threadIdx.x;
    const int base = blockIdx.x * 1024 + tid * 4;
    int v0 = 0, v1 = 0, v2 = 0, v3 = 0;
    if (base + 3 < n) {
        int4 v = *(const int4*)(degi + base);
        v0 = v.x; v1 = v.y; v2 = v.z; v3 = v.w;
    } else {
        if (base + 0 < n) v0 = degi[base + 0];
        if (base + 1 < n) v1 = degi[base + 1];
        if (base + 2 < n) v2 = degi[base + 2];
        if (base + 3 < n) v3 = degi[base + 3];
    }
    int p1 = v0, p2 = v0 + v1, p3 = v0 + v1 + v2, total = p3 + v3;
    ts[tid] = total;
    __syncthreads();
    for (int off = 1; off < 256; off <<= 1) {
        int t = (tid >= off) ? ts[tid - off] : 0;
        __syncthreads();
        ts[tid] += t;
        __syncthreads();
    }
    int eb = (tid ? ts[tid - 1] : 0);
    if (tid == 255) bsums[blockIdx.x] = ts[255];
    if (base + 0 < n) excl[base + 0] = eb;
    if (base + 1 < n) excl[base + 1] = eb + p1;
    if (base + 2 < n) excl[base + 2] = eb + p2;
    if (base + 3 < n) excl[base + 3] = eb + p3;
}

__global__ void scan2(int* __restrict__ bsums, int nb) {
    if (threadIdx.x == 0) {
        int s = 0;
        for (int i = 0; i < nb; ++i) { int t = bsums[i]; bsums[i] = s; s += t; }
    }
}

__global__ void scan3(const int* __restrict__ excl, const int* __restrict__ bsums,
                      int* __restrict__ rowptr, int n, int E) {
    int i = blockIdx.x * 256 + threadIdx.x;
    if (i < n) rowptr[i] = excl[i] + bsums[i >> 10];
    if (i == n) rowptr[n] = E;
}

// ---------------- bucket cursor init from rowptr ----------------------------
__global__ void binit(const int* __restrict__ rowptr, int* __restrict__ gcur, int nb, int n) {
    int b = blockIdx.x * 256 + threadIdx.x;
    if (b < nb) {
        int node0 = b << BSHIFT;
        gcur[b] = rowptr[node0 < n ? node0 : n];
    }
}

// ---------------- pass 1: block-private bucket runs -------------------------
__global__ __launch_bounds__(256) void edge_bin(const int* __restrict__ src,
                                                const int* __restrict__ dst,
                                                int* __restrict__ gcur,
                                                unsigned int* __restrict__ packed, int E) {
    __shared__ int cnt[256];
    __shared__ int cur[256];
    const int tid = threadIdx.x;
    const int e0 = blockIdx.x * CHUNK;
    cnt[tid] = 0;
    __syncthreads();
    for (int i = tid; i < CHUNK; i += 256) {
        int e = e0 + i;
        if (e < E) atomicAdd(&cnt[dst[e] >> BSHIFT], 1);
    }
    __syncthreads();
    cur[tid] = (cnt[tid] > 0) ? atomicAdd(&gcur[tid], cnt[tid]) : 0;
    __syncthreads();
    for (int i = tid; i < CHUNK; i += 256) {
        int e = e0 + i;
        if (e < E) {
            int s = src[e], d = dst[e];
            int pos = atomicAdd(&cur[d >> BSHIFT], 1);
            packed[pos] = ((unsigned)(d & (BNODES - 1)) << SRC_BITS) | (unsigned)s;
        }
    }
}

// ---------------- pass 2: within-bucket exact CSR placement -----------------
__global__ __launch_bounds__(256) void edge_sort(const unsigned int* __restrict__ packed,
                                                 const int* __restrict__ rowptr,
                                                 int* __restrict__ srcs, int n) {
    __shared__ int cur[BNODES];
    const int node0 = blockIdx.x << BSHIFT;
    const int tid = threadIdx.x;
    for (int t = tid; t < BNODES; t += 256) {
        int node = node0 + t;
        if (node < n) cur[t] = rowptr[node];
    }
    __syncthreads();
    const int e0 = rowptr[node0];
    const int e1 = rowptr[min(node0 + BNODES, n)];
    for (int e = e0 + tid; e < e1; e += 256) {
        unsigned p = packed[e];
        int pos = atomicAdd(&cur[p >> SRC_BITS], 1);
        srcs[pos] = (int)(p & ((1u << SRC_BITS) - 1));
    }
}

// ---------------- weight prep (all) + zero pad row of xws -------------------
// Wt1/Wt2: [c][k] = W[k][c] fp16 (16384 each); Wm1t: [c][k] = Wm1[k][c] (8192);
// last 128: zero pad row xws[n*HC..].
__global__ void wprep_all(const float* __restrict__ W1, const float* __restrict__ W2,
                          const float* __restrict__ Wm1,
                          f16* __restrict__ Wt1, f16* __restrict__ Wt2,
                          f16* __restrict__ Wm1t, f16* __restrict__ padrow) {
    int idx = blockIdx.x * 256 + threadIdx.x;
    if (idx < 16384) {
        int k = idx >> 7, c = idx & 127;
        Wt1[(size_t)c * HC + k] = (f16)W1[idx];
    } else if (idx < 32768) {
        int i = idx - 16384;
        int k = i >> 7, c = i & 127;
        Wt2[(size_t)c * HC + k] = (f16)W2[i];
    } else if (idx < 40960) {
        int i = idx - 32768;
        int c = i >> 7, k = i & 127;
        Wm1t[(size_t)c * HC + k] = (f16)Wm1[(size_t)k * 64 + c];
    } else if (idx < 41088) {
        padrow[idx - 40960] = (f16)0.f;
    }
}

// ---------------- MFMA GEMM: Y[row] = dis[row] * (T(X)[row] @ W) ------------
// TRANS=1: BN(scale/shift from stats,gamma,beta)+ReLU applied to X during staging.
template<int SRC_F16, int TRANS>
__global__ __launch_bounds__(256) void gemm_mfma(const void* __restrict__ Xv,
                                                 const f16* __restrict__ Wt,
                                                 const float* __restrict__ stats,
                                                 const float* __restrict__ gamma,
                                                 const float* __restrict__ beta,
                                                 const float* __restrict__ dis,
                                                 f16* __restrict__ Y, int n) {
    __shared__ f16 Ah[64][136];
    __shared__ f16 Bh[128][136];
    __shared__ float sc[HC], sh[HC];
    const int tid  = threadIdx.x;
    const int row0 = blockIdx.x * 64;

    if constexpr (TRANS) {
        if (tid < 128) {
            float s = 0.f, q = 0.f;
#pragma unroll
            for (int t = 0; t < NSTRIPE; ++t) {
                s += stats[t * 256 + tid];
                q += stats[t * 256 + 128 + tid];
            }
            float m = s / (float)n;
            float v = q / (float)n - m * m;
            float scv = gamma[tid] * rsqrtf(fmaxf(v, 0.f) + EPS_BN);
            sc[tid] = scv;
            sh[tid] = beta[tid] - m * scv;
        }
    }

#pragma unroll
    for (int i = 0; i < 8; ++i) {
        int idx = i * 256 + tid;
        int r = idx >> 4, g = idx & 15;
        *(f16x8*)&Bh[r][g * 8] = *(const f16x8*)(Wt + (size_t)r * HC + g * 8);
    }
    __syncthreads();   // sc/sh + Bh visible

#pragma unroll
    for (int i = 0; i < 4; ++i) {
        int idx = i * 256 + tid;
        int r = idx >> 4, g = idx & 15;
        int grow = row0 + r;
        f16x8 h = {};
        if (grow < n) {
            if constexpr (SRC_F16) {
                f16x8 v = *(const f16x8*)((const f16*)Xv + (size_t)grow * HC + g * 8);
                if constexpr (TRANS) {
#pragma unroll
                    for (int j = 0; j < 8; ++j) {
                        float f = (float)v[j];
                        f = fmaxf(fmaf(f, sc[g * 8 + j], sh[g * 8 + j]), 0.f);
                        h[j] = (f16)f;
                    }
                } else h = v;
            } else {
                const float* X = (const float*)Xv;
                float4 a = *(const float4*)(X + (size_t)grow * HC + g * 8);
                float4 c = *(const float4*)(X + (size_t)grow * HC + g * 8 + 4);
                h[0] = (f16)a.x; h[1] = (f16)a.y; h[2] = (f16)a.z; h[3] = (f16)a.w;
                h[4] = (f16)c.x; h[5] = (f16)c.y; h[6] = (f16)c.z; h[7] = (f16)c.w;
            }
        }
        *(f16x8*)&Ah[r][g * 8] = h;
    }
    __syncthreads();

    const int wv   = tid >> 6;
    const int lane = tid & 63;
    const int m    = lane & 15;
    const int kq   = (lane >> 4) * 8;

    f32x4 acc[8] = {};
#pragma unroll
    for (int kc = 0; kc < HC; kc += 32) {
        f16x8 a = *(const f16x8*)&Ah[wv * 16 + m][kc + kq];
#pragma unroll
        for (int t = 0; t < 8; ++t) {
            f16x8 b = *(const f16x8*)&Bh[t * 16 + m][kc + kq];
            acc[t] = __builtin_amdgcn_mfma_f32_16x16x32_f16(a, b, acc[t], 0, 0, 0);
        }
    }

    const int rbase = row0 + wv * 16 + (lane >> 4) * 4;
#pragma unroll
    for (int r = 0; r < 4; ++r) {
        int grow = rbase + r;
        if (grow < n) {
            float dv = dis[grow];
#pragma unroll
            for (int t = 0; t < 8; ++t)
                Y[(size_t)grow * HC + t * 16 + m] = (f16)(acc[t][r] * dv);
        }
    }
}

// ---------------- CSR gather agg on pre-scaled rows -------------------------
// xws[s] = dis[s]*xw[s]; out[v] = dis[v]*(sum_e xws[s] + xws[v]) + b.
// 8 edges in flight per wave-iter; invalid lanes gather zero pad row (index n).
__global__ __launch_bounds__(256) void gcn_agg_f16(const f16* __restrict__ xws,
                                                   const int* __restrict__ srcs,
                                                   const int* __restrict__ rowptr,
                                                   const float* __restrict__ dis,
                                                   const float* __restrict__ bias,
                                                   f16* __restrict__ out,
                                                   float* __restrict__ stats,
                                                   int n, int nwaves) {
    __shared__ float lds_s[4][128], lds_q[4][128];
    const int wv   = threadIdx.x >> 6;
    const int lane = threadIdx.x & 63;
    const int g    = lane >> 4;      // edge subgroup 0..3
    const int cg   = lane & 15;      // channel group (8 channels)

    float b8[8];
#pragma unroll
    for (int j = 0; j < 8; ++j) b8[j] = bias[cg * 8 + j];

    float s8[8] = {}, q8[8] = {};

    for (int node = blockIdx.x * 4 + wv; node < n; node += nwaves) {
        const int e0 = rowptr[node];
        const int e1 = rowptr[node + 1];
        float acc[8] = {};
        for (int e = e0; e < e1; e += 8) {
            int i0 = e + g, i1 = e + g + 4;
            int s0 = (i0 < e1) ? srcs[i0] : n;
            int s1 = (i1 < e1) ? srcs[i1] : n;
            f16x8 v0 = *(const f16x8*)(xws + (size_t)s0 * HC + cg * 8);
            f16x8 v1 = *(const f16x8*)(xws + (size_t)s1 * HC + cg * 8);
#pragma unroll
            for (int j = 0; j < 8; ++j) {
                acc[j] += (float)v0[j];
                acc[j] += (float)v1[j];
            }
        }
#pragma unroll
        for (int j = 0; j < 8; ++j) acc[j] += __shfl_xor(acc[j], 16);
#pragma unroll
        for (int j = 0; j < 8; ++j) acc[j] += __shfl_xor(acc[j], 32);

        if (g == 0) {
            float dv = dis[node];
            f16x8 self = *(const f16x8*)(xws + (size_t)node * HC + cg * 8);
            f16x8 o;
#pragma unroll
            for (int j = 0; j < 8; ++j) {
                float r = fmaf(acc[j] + (float)self[j], dv, b8[j]);
                o[j] = (f16)r;
                s8[j] += r;
                q8[j] += r * r;
            }
            *(f16x8*)(out + (size_t)node * HC + cg * 8) = o;
        }
    }

    if (g == 0) {
#pragma unroll
        for (int j = 0; j < 8; ++j) {
            lds_s[wv][cg * 8 + j] = s8[j];
            lds_q[wv][cg * 8 + j] = q8[j];
        }
    }
    __syncthreads();
    float* stripe = stats + (size_t)(blockIdx.x & (NSTRIPE - 1)) * 256;
    if (threadIdx.x < 128) {
        float s = lds_s[0][threadIdx.x] + lds_s[1][threadIdx.x] +
                  lds_s[2][threadIdx.x] + lds_s[3][threadIdx.x];
        float q = lds_q[0][threadIdx.x] + lds_q[1][threadIdx.x] +
                  lds_q[2][threadIdx.x] + lds_q[3][threadIdx.x];
        atomicAdd(&stripe[threadIdx.x], s);
        atomicAdd(&stripe[128 + threadIdx.x], q);
    }
}

// ---------------- MFMA MLP head (BN2 finalize + BN+ReLU + both layers) ------
// Block: 64 nodes; wave: 16 nodes x 64 hidden via 16 MFMAs; layer-2 folded.
__global__ __launch_bounds__(256) void mlp_mfma(const f16* __restrict__ h,
                                                const float* __restrict__ stats,
                                                const float* __restrict__ gamma,
                                                const float* __restrict__ beta,
                                                const f16* __restrict__ Wm1t,
                                                const float* __restrict__ bm1,
                                                const float* __restrict__ Wm2,
                                                const float* __restrict__ bm2,
                                                float* __restrict__ out, int n) {
    __shared__ f16 Hs[64][136];
    __shared__ f16 Ws[64][136];
    __shared__ float sc[HC], sh[HC], bmv[64], w2v[64];
    const int tid  = threadIdx.x;
    const int row0 = blockIdx.x * 64;

    if (tid < 128) {
        float s = 0.f, q = 0.f;
#pragma unroll
        for (int t = 0; t < NSTRIPE; ++t) {
            s += stats[t * 256 + tid];
            q += stats[t * 256 + 128 + tid];
        }
        float m = s / (float)n;
        float v = q / (float)n - m * m;
        float scv = gamma[tid] * rsqrtf(fmaxf(v, 0.f) + EPS_BN);
        sc[tid] = scv;
        sh[tid] = beta[tid] - m * scv;
    }
    if (tid < 64) { bmv[tid] = bm1[tid]; w2v[tid] = Wm2[tid]; }

    // stage Wm1t (64x128 halves = 1024 groups)
#pragma unroll
    for (int i = 0; i < 4; ++i) {
        int idx = i * 256 + tid;
        int r = idx >> 4, g = idx & 15;
        *(f16x8*)&Ws[r][g * 8] = *(const f16x8*)(Wm1t + (size_t)r * HC + g * 8);
    }
    __syncthreads();

    // stage H with BN2+ReLU
#pragma unroll
    for (int i = 0; i < 4; ++i) {
        int idx = i * 256 + tid;
        int r = idx >> 4, g = idx & 15;
        int grow = row0 + r;
        f16x8 hv = {};
        if (grow < n) {
            f16x8 v = *(const f16x8*)(h + (size_t)grow * HC + g * 8);
#pragma unroll
            for (int j = 0; j < 8; ++j) {
                float f = (float)v[j];
                f = fmaxf(fmaf(f, sc[g * 8 + j], sh[g * 8 + j]), 0.f);
                hv[j] = (f16)f;
            }
        }
        *(f16x8*)&Hs[r][g * 8] = hv;
    }
    __syncthreads();

    const int wv   = tid >> 6;
    const int lane = tid & 63;
    const int m    = lane & 15;
    const int kq   = (lane >> 4) * 8;

    f32x4 acc[4] = {};
#pragma unroll
    for (int kc = 0; kc < HC; kc += 32) {
        f16x8 a = *(const f16x8*)&Hs[wv * 16 + m][kc + kq];
#pragma unroll
        for (int t = 0; t < 4; ++t) {
            f16x8 b = *(const f16x8*)&Ws[t * 16 + m][kc + kq];
            acc[t] = __builtin_amdgcn_mfma_f32_16x16x32_f16(a, b, acc[t], 0, 0, 0);
        }
    }

    // epilogue: col = t*16+m; row = wv*16 + (lane>>4)*4 + reg
    float part[4];
#pragma unroll
    for (int reg = 0; reg < 4; ++reg) {
        float s = 0.f;
#pragma unroll
        for (int t = 0; t < 4; ++t) {
            int col = t * 16 + m;
            float val = fmaxf(acc[t][reg] + bmv[col], 0.f) * w2v[col];
            s += val;
        }
        part[reg] = s;
    }
#pragma unroll
    for (int off = 1; off < 16; off <<= 1) {
#pragma unroll
        for (int reg = 0; reg < 4; ++reg)
            part[reg] += __shfl_xor(part[reg], off);
    }
    if (m == 0) {
        int rbase = row0 + wv * 16 + (lane >> 4) * 4;
        float bb = bm2[0];
#pragma unroll
        for (int reg = 0; reg < 4; ++reg) {
            int row = rbase + reg;
            if (row < n) out[row] = part[reg] + bb;
        }
    }
}

extern "C" void kernel_launch(void* const* d_in, const int* in_sizes, int n_in,
                              void* d_out, int out_size, void* d_ws, size_t ws_size,
                              hipStream_t stream) {
    const float* x   = (const float*)d_in[0];
    const int*   ei  = (const int*)  d_in[1];
    const float* W1  = (const float*)d_in[2];
    const float* b1  = (const float*)d_in[3];
    const float* g1  = (const float*)d_in[4];
    const float* be1 = (const float*)d_in[5];
    const float* W2  = (const float*)d_in[6];
    const float* b2  = (const float*)d_in[7];
    const float* g2  = (const float*)d_in[8];
    const float* be2 = (const float*)d_in[9];
    const float* Wm1 = (const float*)d_in[10];
    const float* bm1 = (const float*)d_in[11];
    const float* Wm2 = (const float*)d_in[12];
    const float* bm2 = (const float*)d_in[13];
    float* out = (float*)d_out;

    const int n = in_sizes[0] / HC;       // 100000
    const int E = in_sizes[1] / 2;        // 1600000
    const int* srcp = ei;
    const int* dstp = ei + E;
    const int nb = (n + BNODES - 1) >> BSHIFT;   // 196 buckets

    char* ws = (char*)d_ws;
    size_t off = 0;
    auto alloc = [&](size_t bytes) { void* p = ws + off; off = (off + bytes + 511) & ~511ULL; return p; };
    float*  dis    = (float*) alloc((size_t)n * 4);
    int*    degi   = (int*)   alloc((size_t)n * 4);
    int*    excl   = (int*)   alloc((size_t)n * 4);
    int*    rowptr = (int*)   alloc((size_t)(n + 1) * 4);
    int*    bsums  = (int*)   alloc(4096);
    int*    gcur   = (int*)   alloc(1024);
    unsigned int* packed = (unsigned int*)alloc((size_t)E * 4);
    int*    srcs   = (int*)   alloc((size_t)E * 4);
    f16*    xws    = (f16*)   alloc((size_t)(n + 1) * HC * 2);   // +1 zero pad row
    f16*    bufBh  = (f16*)   alloc((size_t)n * HC * 2);
    f16*    Wt1    = (f16*)   alloc((size_t)HC * HC * 2);
    f16*    Wt2    = (f16*)   alloc((size_t)HC * HC * 2);
    f16*    Wm1t   = (f16*)   alloc((size_t)64 * HC * 2);
    float*  stats1 = (float*) alloc(NSTRIPE * 256 * 4);
    float*  stats2 = (float*) alloc(NSTRIPE * 256 * 4);

    const int gemmBlocks  = (n + 63) / 64;
    const int nScanBlocks = (n + 1023) / 1024;
    const int binBlocks   = (E + CHUNK - 1) / CHUNK;
    const int aggWaves    = AGG_BLOCKS * 4;

    // ---- zero init ----
    hipMemsetAsync(degi, 0, (size_t)n * 4, stream);
    hipMemsetAsync(stats1, 0, NSTRIPE * 256 * 4, stream);
    hipMemsetAsync(stats2, 0, NSTRIPE * 256 * 4, stream);

    // ---- CSR build (shared by both layers) ----
    degi_kernel<<<(E + 255) / 256, 256, 0, stream>>>(dstp, degi, E);
    dis_kernel<<<(n + 255) / 256, 256, 0, stream>>>(degi, dis, n);
    scan1<<<nScanBlocks, 256, 0, stream>>>(degi, excl, bsums, n);
    scan2<<<1, 64, 0, stream>>>(bsums, nScanBlocks);
    scan3<<<(n + 256) / 256, 256, 0, stream>>>(excl, bsums, rowptr, n, E);
    binit<<<1, 256, 0, stream>>>(rowptr, gcur, nb, n);
    edge_bin<<<binBlocks, 256, 0, stream>>>(srcp, dstp, gcur, packed, E);
    edge_sort<<<nb, 256, 0, stream>>>(packed, rowptr, srcs, n);

    // ---- weight prep + pad row zero ----
    wprep_all<<<(41088 + 255) / 256, 256, 0, stream>>>(W1, W2, Wm1, Wt1, Wt2, Wm1t,
                                                       xws + (size_t)n * HC);

    // ---- layer 1 ----
    gemm_mfma<0, 0><<<gemmBlocks, 256, 0, stream>>>(x, Wt1, nullptr, nullptr, nullptr,
                                                    dis, xws, n);
    gcn_agg_f16<<<AGG_BLOCKS, 256, 0, stream>>>(xws, srcs, rowptr, dis, b1,
                                                bufBh, stats1, n, aggWaves);

    // ---- layer 2 (BN1 finalize + BN+ReLU fused into GEMM staging) ----
    gemm_mfma<1, 1><<<gemmBlocks, 256, 0, stream>>>(bufBh, Wt2, stats1, g1, be1,
                                                    dis, xws, n);
    gcn_agg_f16<<<AGG_BLOCKS, 256, 0, stream>>>(xws, srcs, rowptr, dis, b2,
                                                bufBh, stats2, n, aggWaves);

    // ---- MLP head (BN2 finalize + BN+ReLU + both layers fused, MFMA) ----
    mlp_mfma<<<gemmBlocks, 256, 0, stream>>>(bufBh, stats2, g2, be2, Wm1t, bm1, Wm2, bm2,
                                             out, n);
}

// Round 10
// 363.079 us; speedup vs baseline: 2.2645x; 1.1566x over previous
//
#include <hip/hip_runtime.h>
#include <hip/hip_fp16.h>

#define HC 128
#define EPS_BN 1e-5f
#define NSTRIPE 8
#define AGG_BLOCKS 3072
#define BSHIFT 9                 // 512 nodes per bucket
#define BNODES (1 << BSHIFT)
#define CHUNK 8192               // edges per pass-1 block
#define SRC_BITS 18              // src < 2^18

typedef _Float16 f16;
typedef f16  f16x8 __attribute__((ext_vector_type(8)));
typedef float f32x4 __attribute__((ext_vector_type(4)));

// ---------------- A1: per-bucket histogram ----------------------------------
__global__ __launch_bounds__(256) void bucket_count(const int* __restrict__ dst,
                                                    int* __restrict__ bcnt, int E) {
    __shared__ int c[256];
    const int tid = threadIdx.x;
    const int e0 = blockIdx.x * CHUNK;
    c[tid] = 0;
    __syncthreads();
    for (int i = tid; i < CHUNK; i += 256) {
        int e = e0 + i;
        if (e < E) atomicAdd(&c[dst[e] >> BSHIFT], 1);
    }
    __syncthreads();
    if (c[tid] > 0) atomicAdd(&bcnt[tid], c[tid]);
}

// ---------------- A2: scan buckets -> bbase, gcur; rowptr[n]=E --------------
__global__ __launch_bounds__(256) void bscan(const int* __restrict__ bcnt,
                                             int* __restrict__ bbase, int* __restrict__ gcur,
                                             int* __restrict__ rowptr, int nb, int n, int E) {
    __shared__ int s[256];
    const int tid = threadIdx.x;
    s[tid] = (tid < nb) ? bcnt[tid] : 0;
    __syncthreads();
    for (int off = 1; off < 256; off <<= 1) {
        int t = (tid >= off) ? s[tid - off] : 0;
        __syncthreads();
        s[tid] += t;
        __syncthreads();
    }
    int excl = tid ? s[tid - 1] : 0;
    if (tid < nb) { bbase[tid] = excl; gcur[tid] = excl; }
    if (tid == 0) { bbase[nb] = E; rowptr[n] = E; }
}

// ---------------- pass 1: block-private bucket runs -------------------------
__global__ __launch_bounds__(256) void edge_bin(const int* __restrict__ src,
                                                const int* __restrict__ dst,
                                                int* __restrict__ gcur,
                                                unsigned int* __restrict__ packed, int E) {
    __shared__ int cnt[256];
    __shared__ int cur[256];
    const int tid = threadIdx.x;
    const int e0 = blockIdx.x * CHUNK;
    cnt[tid] = 0;
    __syncthreads();
    for (int i = tid; i < CHUNK; i += 256) {
        int e = e0 + i;
        if (e < E) atomicAdd(&cnt[dst[e] >> BSHIFT], 1);
    }
    __syncthreads();
    cur[tid] = (cnt[tid] > 0) ? atomicAdd(&gcur[tid], cnt[tid]) : 0;
    __syncthreads();
    for (int i = tid; i < CHUNK; i += 256) {
        int e = e0 + i;
        if (e < E) {
            int s = src[e], d = dst[e];
            int pos = atomicAdd(&cur[d >> BSHIFT], 1);
            packed[pos] = ((unsigned)(d & (BNODES - 1)) << SRC_BITS) | (unsigned)s;
        }
    }
}

// ---------------- pass 2: per-bucket degree+scan+placement ------------------
// Emits rowptr, dis, and CSR srcs for the bucket's 512 nodes.
__global__ __launch_bounds__(256) void edge_sort(const unsigned int* __restrict__ packed,
                                                 const int* __restrict__ bbase,
                                                 int* __restrict__ rowptr,
                                                 float* __restrict__ dis,
                                                 int* __restrict__ srcs, int n) {
    __shared__ int cnt[BNODES];
    __shared__ int cur[BNODES];
    __shared__ int scn[256];
    const int b = blockIdx.x;
    const int node0 = b << BSHIFT;
    const int tid = threadIdx.x;
    const int base = bbase[b];
    const int end  = bbase[b + 1];

    cnt[tid] = 0; cnt[tid + 256] = 0;
    __syncthreads();
    for (int e = base + tid; e < end; e += 256)
        atomicAdd(&cnt[packed[e] >> SRC_BITS], 1);
    __syncthreads();
    int p0 = cnt[2 * tid], p1 = cnt[2 * tid + 1];
    scn[tid] = p0 + p1;
    __syncthreads();
    for (int off = 1; off < 256; off <<= 1) {
        int t = (tid >= off) ? scn[tid - off] : 0;
        __syncthreads();
        scn[tid] += t;
        __syncthreads();
    }
    int eb = tid ? scn[tid - 1] : 0;
    {
        int nodeA = node0 + 2 * tid;
        int nodeB = nodeA + 1;
        if (nodeA < n) { rowptr[nodeA] = base + eb;      dis[nodeA] = rsqrtf((float)p0 + 1.f); }
        if (nodeB < n) { rowptr[nodeB] = base + eb + p0; dis[nodeB] = rsqrtf((float)p1 + 1.f); }
    }
    cur[2 * tid] = eb;
    cur[2 * tid + 1] = eb + p0;
    __syncthreads();
    for (int e = base + tid; e < end; e += 256) {
        unsigned p = packed[e];
        int pos = atomicAdd(&cur[p >> SRC_BITS], 1);
        srcs[base + pos] = (int)(p & ((1u << SRC_BITS) - 1));
    }
}

// ---------------- weight prep (all) + zero pad row of xws -------------------
__global__ void wprep_all(const float* __restrict__ W1, const float* __restrict__ W2,
                          const float* __restrict__ Wm1,
                          f16* __restrict__ Wt1, f16* __restrict__ Wt2,
                          f16* __restrict__ Wm1t, f16* __restrict__ padrow) {
    int idx = blockIdx.x * 256 + threadIdx.x;
    if (idx < 16384) {
        int k = idx >> 7, c = idx & 127;
        Wt1[(size_t)c * HC + k] = (f16)W1[idx];
    } else if (idx < 32768) {
        int i = idx - 16384;
        int k = i >> 7, c = i & 127;
        Wt2[(size_t)c * HC + k] = (f16)W2[i];
    } else if (idx < 40960) {
        int i = idx - 32768;
        int c = i >> 7, k = i & 127;
        Wm1t[(size_t)c * HC + k] = (f16)Wm1[(size_t)k * 64 + c];
    } else if (idx < 41088) {
        padrow[idx - 40960] = (f16)0.f;
    }
}

// ---------------- MFMA GEMM: Y[row] = dis[row] * (T(X)[row] @ W) ------------
template<int SRC_F16, int TRANS>
__global__ __launch_bounds__(256) void gemm_mfma(const void* __restrict__ Xv,
                                                 const f16* __restrict__ Wt,
                                                 const float* __restrict__ stats,
                                                 const float* __restrict__ gamma,
                                                 const float* __restrict__ beta,
                                                 const float* __restrict__ dis,
                                                 f16* __restrict__ Y, int n) {
    __shared__ f16 Ah[64][136];
    __shared__ f16 Bh[128][136];
    __shared__ float sc[HC], sh[HC];
    const int tid  = threadIdx.x;
    const int row0 = blockIdx.x * 64;

    if constexpr (TRANS) {
        if (tid < 128) {
            float s = 0.f, q = 0.f;
#pragma unroll
            for (int t = 0; t < NSTRIPE; ++t) {
                s += stats[t * 256 + tid];
                q += stats[t * 256 + 128 + tid];
            }
            float m = s / (float)n;
            float v = q / (float)n - m * m;
            float scv = gamma[tid] * rsqrtf(fmaxf(v, 0.f) + EPS_BN);
            sc[tid] = scv;
            sh[tid] = beta[tid] - m * scv;
        }
    }

#pragma unroll
    for (int i = 0; i < 8; ++i) {
        int idx = i * 256 + tid;
        int r = idx >> 4, g = idx & 15;
        *(f16x8*)&Bh[r][g * 8] = *(const f16x8*)(Wt + (size_t)r * HC + g * 8);
    }
    __syncthreads();

#pragma unroll
    for (int i = 0; i < 4; ++i) {
        int idx = i * 256 + tid;
        int r = idx >> 4, g = idx & 15;
        int grow = row0 + r;
        f16x8 h = {};
        if (grow < n) {
            if constexpr (SRC_F16) {
                f16x8 v = *(const f16x8*)((const f16*)Xv + (size_t)grow * HC + g * 8);
                if constexpr (TRANS) {
#pragma unroll
                    for (int j = 0; j < 8; ++j) {
                        float f = (float)v[j];
                        f = fmaxf(fmaf(f, sc[g * 8 + j], sh[g * 8 + j]), 0.f);
                        h[j] = (f16)f;
                    }
                } else h = v;
            } else {
                const float* X = (const float*)Xv;
                float4 a = *(const float4*)(X + (size_t)grow * HC + g * 8);
                float4 c = *(const float4*)(X + (size_t)grow * HC + g * 8 + 4);
                h[0] = (f16)a.x; h[1] = (f16)a.y; h[2] = (f16)a.z; h[3] = (f16)a.w;
                h[4] = (f16)c.x; h[5] = (f16)c.y; h[6] = (f16)c.z; h[7] = (f16)c.w;
            }
        }
        *(f16x8*)&Ah[r][g * 8] = h;
    }
    __syncthreads();

    const int wv   = tid >> 6;
    const int lane = tid & 63;
    const int m    = lane & 15;
    const int kq   = (lane >> 4) * 8;

    f32x4 acc[8] = {};
#pragma unroll
    for (int kc = 0; kc < HC; kc += 32) {
        f16x8 a = *(const f16x8*)&Ah[wv * 16 + m][kc + kq];
#pragma unroll
        for (int t = 0; t < 8; ++t) {
            f16x8 b = *(const f16x8*)&Bh[t * 16 + m][kc + kq];
            acc[t] = __builtin_amdgcn_mfma_f32_16x16x32_f16(a, b, acc[t], 0, 0, 0);
        }
    }

    const int rbase = row0 + wv * 16 + (lane >> 4) * 4;
#pragma unroll
    for (int r = 0; r < 4; ++r) {
        int grow = rbase + r;
        if (grow < n) {
            float dv = dis[grow];
#pragma unroll
            for (int t = 0; t < 8; ++t)
                Y[(size_t)grow * HC + t * 16 + m] = (f16)(acc[t][r] * dv);
        }
    }
}

// ---------------- CSR gather agg, 16 edges in flight ------------------------
// xws[s] = dis[s]*xw[s]; out[v] = dis[v]*(sum_e xws[s] + xws[v]) + b.
__global__ __launch_bounds__(256) void gcn_agg_f16(const f16* __restrict__ xws,
                                                   const int* __restrict__ srcs,
                                                   const int* __restrict__ rowptr,
                                                   const float* __restrict__ dis,
                                                   const float* __restrict__ bias,
                                                   f16* __restrict__ out,
                                                   float* __restrict__ stats,
                                                   int n, int nwaves) {
    __shared__ float lds_s[4][128], lds_q[4][128];
    const int wv   = threadIdx.x >> 6;
    const int lane = threadIdx.x & 63;
    const int g    = lane >> 4;      // edge subgroup 0..3
    const int cg   = lane & 15;      // channel group (8 channels)

    float b8[8];
#pragma unroll
    for (int j = 0; j < 8; ++j) b8[j] = bias[cg * 8 + j];

    float s8[8] = {}, q8[8] = {};

    for (int node = blockIdx.x * 4 + wv; node < n; node += nwaves) {
        const int e0 = rowptr[node];
        const int e1 = rowptr[node + 1];
        float acc[8] = {};
        for (int e = e0; e < e1; e += 16) {
            int i0 = e + g;
            int s0 = (i0      < e1) ? srcs[i0]      : n;
            int s1 = (i0 + 4  < e1) ? srcs[i0 + 4]  : n;
            int s2 = (i0 + 8  < e1) ? srcs[i0 + 8]  : n;
            int s3 = (i0 + 12 < e1) ? srcs[i0 + 12] : n;
            f16x8 v0 = *(const f16x8*)(xws + (size_t)s0 * HC + cg * 8);
            f16x8 v1 = *(const f16x8*)(xws + (size_t)s1 * HC + cg * 8);
            f16x8 v2 = *(const f16x8*)(xws + (size_t)s2 * HC + cg * 8);
            f16x8 v3 = *(const f16x8*)(xws + (size_t)s3 * HC + cg * 8);
#pragma unroll
            for (int j = 0; j < 8; ++j)
                acc[j] += ((float)v0[j] + (float)v1[j]) + ((float)v2[j] + (float)v3[j]);
        }
#pragma unroll
        for (int j = 0; j < 8; ++j) acc[j] += __shfl_xor(acc[j], 16);
#pragma unroll
        for (int j = 0; j < 8; ++j) acc[j] += __shfl_xor(acc[j], 32);

        if (g == 0) {
            float dv = dis[node];
            f16x8 self = *(const f16x8*)(xws + (size_t)node * HC + cg * 8);
            f16x8 o;
#pragma unroll
            for (int j = 0; j < 8; ++j) {
                float r = fmaf(acc[j] + (float)self[j], dv, b8[j]);
                o[j] = (f16)r;
                s8[j] += r;
                q8[j] += r * r;
            }
            *(f16x8*)(out + (size_t)node * HC + cg * 8) = o;
        }
    }

    if (g == 0) {
#pragma unroll
        for (int j = 0; j < 8; ++j) {
            lds_s[wv][cg * 8 + j] = s8[j];
            lds_q[wv][cg * 8 + j] = q8[j];
        }
    }
    __syncthreads();
    float* stripe = stats + (size_t)(blockIdx.x & (NSTRIPE - 1)) * 256;
    if (threadIdx.x < 128) {
        float s = lds_s[0][threadIdx.x] + lds_s[1][threadIdx.x] +
                  lds_s[2][threadIdx.x] + lds_s[3][threadIdx.x];
        float q = lds_q[0][threadIdx.x] + lds_q[1][threadIdx.x] +
                  lds_q[2][threadIdx.x] + lds_q[3][threadIdx.x];
        atomicAdd(&stripe[threadIdx.x], s);
        atomicAdd(&stripe[128 + threadIdx.x], q);
    }
}

// ---------------- MFMA MLP head (BN2 finalize + BN+ReLU + both layers) ------
__global__ __launch_bounds__(256) void mlp_mfma(const f16* __restrict__ h,
                                                const float* __restrict__ stats,
                                                const float* __restrict__ gamma,
                                                const float* __restrict__ beta,
                                                const f16* __restrict__ Wm1t,
                                                const float* __restrict__ bm1,
                                                const float* __restrict__ Wm2,
                                                const float* __restrict__ bm2,
                                                float* __restrict__ out, int n) {
    __shared__ f16 Hs[64][136];
    __shared__ f16 Ws[64][136];
    __shared__ float sc[HC], sh[HC], bmv[64], w2v[64];
    const int tid  = threadIdx.x;
    const int row0 = blockIdx.x * 64;

    if (tid < 128) {
        float s = 0.f, q = 0.f;
#pragma unroll
        for (int t = 0; t < NSTRIPE; ++t) {
            s += stats[t * 256 + tid];
            q += stats[t * 256 + 128 + tid];
        }
        float m = s / (float)n;
        float v = q / (float)n - m * m;
        float scv = gamma[tid] * rsqrtf(fmaxf(v, 0.f) + EPS_BN);
        sc[tid] = scv;
        sh[tid] = beta[tid] - m * scv;
    }
    if (tid < 64) { bmv[tid] = bm1[tid]; w2v[tid] = Wm2[tid]; }

#pragma unroll
    for (int i = 0; i < 4; ++i) {
        int idx = i * 256 + tid;
        int r = idx >> 4, g = idx & 15;
        *(f16x8*)&Ws[r][g * 8] = *(const f16x8*)(Wm1t + (size_t)r * HC + g * 8);
    }
    __syncthreads();

#pragma unroll
    for (int i = 0; i < 4; ++i) {
        int idx = i * 256 + tid;
        int r = idx >> 4, g = idx & 15;
        int grow = row0 + r;
        f16x8 hv = {};
        if (grow < n) {
            f16x8 v = *(const f16x8*)(h + (size_t)grow * HC + g * 8);
#pragma unroll
            for (int j = 0; j < 8; ++j) {
                float f = (float)v[j];
                f = fmaxf(fmaf(f, sc[g * 8 + j], sh[g * 8 + j]), 0.f);
                hv[j] = (f16)f;
            }
        }
        *(f16x8*)&Hs[r][g * 8] = hv;
    }
    __syncthreads();

    const int wv   = tid >> 6;
    const int lane = tid & 63;
    const int m    = lane & 15;
    const int kq   = (lane >> 4) * 8;

    f32x4 acc[4] = {};
#pragma unroll
    for (int kc = 0; kc < HC; kc += 32) {
        f16x8 a = *(const f16x8*)&Hs[wv * 16 + m][kc + kq];
#pragma unroll
        for (int t = 0; t < 4; ++t) {
            f16x8 b = *(const f16x8*)&Ws[t * 16 + m][kc + kq];
            acc[t] = __builtin_amdgcn_mfma_f32_16x16x32_f16(a, b, acc[t], 0, 0, 0);
        }
    }

    float part[4];
#pragma unroll
    for (int reg = 0; reg < 4; ++reg) {
        float s = 0.f;
#pragma unroll
        for (int t = 0; t < 4; ++t) {
            int col = t * 16 + m;
            s += fmaxf(acc[t][reg] + bmv[col], 0.f) * w2v[col];
        }
        part[reg] = s;
    }
#pragma unroll
    for (int off = 1; off < 16; off <<= 1) {
#pragma unroll
        for (int reg = 0; reg < 4; ++reg)
            part[reg] += __shfl_xor(part[reg], off);
    }
    if (m == 0) {
        int rbase = row0 + wv * 16 + (lane >> 4) * 4;
        float bb = bm2[0];
#pragma unroll
        for (int reg = 0; reg < 4; ++reg) {
            int row = rbase + reg;
            if (row < n) out[row] = part[reg] + bb;
        }
    }
}

extern "C" void kernel_launch(void* const* d_in, const int* in_sizes, int n_in,
                              void* d_out, int out_size, void* d_ws, size_t ws_size,
                              hipStream_t stream) {
    const float* x   = (const float*)d_in[0];
    const int*   ei  = (const int*)  d_in[1];
    const float* W1  = (const float*)d_in[2];
    const float* b1  = (const float*)d_in[3];
    const float* g1  = (const float*)d_in[4];
    const float* be1 = (const float*)d_in[5];
    const float* W2  = (const float*)d_in[6];
    const float* b2  = (const float*)d_in[7];
    const float* g2  = (const float*)d_in[8];
    const float* be2 = (const float*)d_in[9];
    const float* Wm1 = (const float*)d_in[10];
    const float* bm1 = (const float*)d_in[11];
    const float* Wm2 = (const float*)d_in[12];
    const float* bm2 = (const float*)d_in[13];
    float* out = (float*)d_out;

    const int n = in_sizes[0] / HC;       // 100000
    const int E = in_sizes[1] / 2;        // 1600000
    const int* srcp = ei;
    const int* dstp = ei + E;
    const int nb = (n + BNODES - 1) >> BSHIFT;   // 196 buckets

    char* ws = (char*)d_ws;
    size_t off = 0;
    auto alloc = [&](size_t bytes) { void* p = ws + off; off = (off + bytes + 511) & ~511ULL; return p; };
    float*  dis    = (float*) alloc((size_t)n * 4);
    int*    rowptr = (int*)   alloc((size_t)(n + 1) * 4);
    int*    bcnt   = (int*)   alloc(1024);
    int*    bbase  = (int*)   alloc(1024 + 4);
    int*    gcur   = (int*)   alloc(1024);
    unsigned int* packed = (unsigned int*)alloc((size_t)E * 4);
    int*    srcs   = (int*)   alloc((size_t)E * 4);
    f16*    xws    = (f16*)   alloc((size_t)(n + 1) * HC * 2);   // +1 zero pad row
    f16*    bufBh  = (f16*)   alloc((size_t)n * HC * 2);
    f16*    Wt1    = (f16*)   alloc((size_t)HC * HC * 2);
    f16*    Wt2    = (f16*)   alloc((size_t)HC * HC * 2);
    f16*    Wm1t   = (f16*)   alloc((size_t)64 * HC * 2);
    float*  stats1 = (float*) alloc(NSTRIPE * 256 * 4);
    float*  stats2 = (float*) alloc(NSTRIPE * 256 * 4);

    const int gemmBlocks = (n + 63) / 64;
    const int binBlocks  = (E + CHUNK - 1) / CHUNK;
    const int aggWaves   = AGG_BLOCKS * 4;

    // ---- zero init ----
    hipMemsetAsync(bcnt, 0, 1024, stream);
    hipMemsetAsync(stats1, 0, NSTRIPE * 256 * 4, stream);
    hipMemsetAsync(stats2, 0, NSTRIPE * 256 * 4, stream);

    // ---- CSR build: bucket histogram -> scan -> bin -> per-bucket sort ----
    bucket_count<<<binBlocks, 256, 0, stream>>>(dstp, bcnt, E);
    bscan<<<1, 256, 0, stream>>>(bcnt, bbase, gcur, rowptr, nb, n, E);
    edge_bin<<<binBlocks, 256, 0, stream>>>(srcp, dstp, gcur, packed, E);
    edge_sort<<<nb, 256, 0, stream>>>(packed, bbase, rowptr, dis, srcs, n);

    // ---- weight prep + pad row zero ----
    wprep_all<<<(41088 + 255) / 256, 256, 0, stream>>>(W1, W2, Wm1, Wt1, Wt2, Wm1t,
                                                       xws + (size_t)n * HC);

    // ---- layer 1 ----
    gemm_mfma<0, 0><<<gemmBlocks, 256, 0, stream>>>(x, Wt1, nullptr, nullptr, nullptr,
                                                    dis, xws, n);
    gcn_agg_f16<<<AGG_BLOCKS, 256, 0, stream>>>(xws, srcs, rowptr, dis, b1,
                                                bufBh, stats1, n, aggWaves);

    // ---- layer 2 (BN1 finalize + BN+ReLU fused into GEMM staging) ----
    gemm_mfma<1, 1><<<gemmBlocks, 256, 0, stream>>>(bufBh, Wt2, stats1, g1, be1,
                                                    dis, xws, n);
    gcn_agg_f16<<<AGG_BLOCKS, 256, 0, stream>>>(xws, srcs, rowptr, dis, b2,
                                                bufBh, stats2, n, aggWaves);

    // ---- MLP head (BN2 finalize + BN+ReLU + both layers fused, MFMA) ----
    mlp_mfma<<<gemmBlocks, 256, 0, stream>>>(bufBh, stats2, g2, be2, Wm1t, bm1, Wm2, bm2,
                                             out, n);
}

// Round 11
// 329.603 us; speedup vs baseline: 2.4945x; 1.1016x over previous
//
#include <hip/hip_runtime.h>
#include <hip/hip_fp16.h>

#define HC 128
#define EPS_BN 1e-5f
#define NSTRIPE 8
#define AGG_BLOCKS 3072
#define BSHIFT 9                 // 512 nodes per bucket
#define BNODES (1 << BSHIFT)
#define CHUNK 8192               // edges per pass-1 block
#define SRC_BITS 18              // src < 2^18

typedef _Float16 f16;
typedef f16  f16x8 __attribute__((ext_vector_type(8)));
typedef float f32x4 __attribute__((ext_vector_type(4)));

// ---------------- A1: per-bucket histogram (1024 thr for TLP) ---------------
__global__ __launch_bounds__(1024) void bucket_count(const int* __restrict__ dst,
                                                     int* __restrict__ bcnt, int E) {
    __shared__ int c[256];
    const int tid = threadIdx.x;
    const int e0 = blockIdx.x * CHUNK;
    if (tid < 256) c[tid] = 0;
    __syncthreads();
    for (int i = tid; i < CHUNK; i += 1024) {
        int e = e0 + i;
        if (e < E) atomicAdd(&c[dst[e] >> BSHIFT], 1);
    }
    __syncthreads();
    if (tid < 256 && c[tid] > 0) atomicAdd(&bcnt[tid], c[tid]);
}

// ---------------- A2: scan buckets -> bbase, gcur; rowptr[n]=E --------------
__global__ __launch_bounds__(256) void bscan(const int* __restrict__ bcnt,
                                             int* __restrict__ bbase, int* __restrict__ gcur,
                                             int* __restrict__ rowptr, int nb, int n, int E) {
    __shared__ int s[256];
    const int tid = threadIdx.x;
    s[tid] = (tid < nb) ? bcnt[tid] : 0;
    __syncthreads();
    for (int off = 1; off < 256; off <<= 1) {
        int t = (tid >= off) ? s[tid - off] : 0;
        __syncthreads();
        s[tid] += t;
        __syncthreads();
    }
    int excl = tid ? s[tid - 1] : 0;
    if (tid < nb) { bbase[tid] = excl; gcur[tid] = excl; }
    if (tid == 0) { bbase[nb] = E; rowptr[n] = E; }
}

// ---------------- pass 1: block-private bucket runs (1024 thr) --------------
__global__ __launch_bounds__(1024) void edge_bin(const int* __restrict__ src,
                                                 const int* __restrict__ dst,
                                                 int* __restrict__ gcur,
                                                 unsigned int* __restrict__ packed, int E) {
    __shared__ int cnt[256];
    __shared__ int cur[256];
    const int tid = threadIdx.x;
    const int e0 = blockIdx.x * CHUNK;
    if (tid < 256) cnt[tid] = 0;
    __syncthreads();
    for (int i = tid; i < CHUNK; i += 1024) {
        int e = e0 + i;
        if (e < E) atomicAdd(&cnt[dst[e] >> BSHIFT], 1);
    }
    __syncthreads();
    if (tid < 256) cur[tid] = (cnt[tid] > 0) ? atomicAdd(&gcur[tid], cnt[tid]) : 0;
    __syncthreads();
    for (int i = tid; i < CHUNK; i += 1024) {
        int e = e0 + i;
        if (e < E) {
            int s = src[e], d = dst[e];
            int pos = atomicAdd(&cur[d >> BSHIFT], 1);
            packed[pos] = ((unsigned)(d & (BNODES - 1)) << SRC_BITS) | (unsigned)s;
        }
    }
}

// ---------------- pass 2: per-bucket degree+scan+placement (1024 thr) -------
__global__ __launch_bounds__(1024) void edge_sort(const unsigned int* __restrict__ packed,
                                                  const int* __restrict__ bbase,
                                                  int* __restrict__ rowptr,
                                                  float* __restrict__ dis,
                                                  int* __restrict__ srcs, int n) {
    __shared__ int cnt[BNODES];
    __shared__ int cur[BNODES];
    __shared__ int scn[BNODES];
    const int b = blockIdx.x;
    const int node0 = b << BSHIFT;
    const int tid = threadIdx.x;
    const int base = bbase[b];
    const int end  = bbase[b + 1];

    if (tid < BNODES) cnt[tid] = 0;
    __syncthreads();
    for (int e = base + tid; e < end; e += 1024)
        atomicAdd(&cnt[packed[e] >> SRC_BITS], 1);
    __syncthreads();
    if (tid < BNODES) scn[tid] = cnt[tid];
    __syncthreads();
    for (int off = 1; off < BNODES; off <<= 1) {
        int t = 0;
        if (tid < BNODES && tid >= off) t = scn[tid - off];
        __syncthreads();
        if (tid < BNODES) scn[tid] += t;
        __syncthreads();
    }
    if (tid < BNODES) {
        int excl = scn[tid] - cnt[tid];
        int node = node0 + tid;
        if (node < n) {
            rowptr[node] = base + excl;
            dis[node] = rsqrtf((float)cnt[tid] + 1.f);
        }
        cur[tid] = excl;
    }
    __syncthreads();
    for (int e = base + tid; e < end; e += 1024) {
        unsigned p = packed[e];
        int pos = atomicAdd(&cur[p >> SRC_BITS], 1);
        srcs[base + pos] = (int)(p & ((1u << SRC_BITS) - 1));
    }
}

// ---------------- weight prep (all) + zero pad row of xws -------------------
__global__ void wprep_all(const float* __restrict__ W1, const float* __restrict__ W2,
                          const float* __restrict__ Wm1,
                          f16* __restrict__ Wt1, f16* __restrict__ Wt2,
                          f16* __restrict__ Wm1t, f16* __restrict__ padrow) {
    int idx = blockIdx.x * 256 + threadIdx.x;
    if (idx < 16384) {
        int k = idx >> 7, c = idx & 127;
        Wt1[(size_t)c * HC + k] = (f16)W1[idx];
    } else if (idx < 32768) {
        int i = idx - 16384;
        int k = i >> 7, c = i & 127;
        Wt2[(size_t)c * HC + k] = (f16)W2[i];
    } else if (idx < 40960) {
        int i = idx - 32768;
        int c = i >> 7, k = i & 127;
        Wm1t[(size_t)c * HC + k] = (f16)Wm1[(size_t)k * 64 + c];
    } else if (idx < 41088) {
        padrow[idx - 40960] = (f16)0.f;
    }
}

// ---------------- MFMA GEMM: Y[row] = dis[row] * (T(X)[row] @ W) ------------
template<int SRC_F16, int TRANS>
__global__ __launch_bounds__(256) void gemm_mfma(const void* __restrict__ Xv,
                                                 const f16* __restrict__ Wt,
                                                 const float* __restrict__ stats,
                                                 const float* __restrict__ gamma,
                                                 const float* __restrict__ beta,
                                                 const float* __restrict__ dis,
                                                 f16* __restrict__ Y, int n) {
    __shared__ f16 Ah[64][136];
    __shared__ f16 Bh[128][136];
    __shared__ float sc[HC], sh[HC];
    const int tid  = threadIdx.x;
    const int row0 = blockIdx.x * 64;

    if constexpr (TRANS) {
        if (tid < 128) {
            float s = 0.f, q = 0.f;
#pragma unroll
            for (int t = 0; t < NSTRIPE; ++t) {
                s += stats[t * 256 + tid];
                q += stats[t * 256 + 128 + tid];
            }
            float m = s / (float)n;
            float v = q / (float)n - m * m;
            float scv = gamma[tid] * rsqrtf(fmaxf(v, 0.f) + EPS_BN);
            sc[tid] = scv;
            sh[tid] = beta[tid] - m * scv;
        }
    }

#pragma unroll
    for (int i = 0; i < 8; ++i) {
        int idx = i * 256 + tid;
        int r = idx >> 4, g = idx & 15;
        *(f16x8*)&Bh[r][g * 8] = *(const f16x8*)(Wt + (size_t)r * HC + g * 8);
    }
    __syncthreads();

#pragma unroll
    for (int i = 0; i < 4; ++i) {
        int idx = i * 256 + tid;
        int r = idx >> 4, g = idx & 15;
        int grow = row0 + r;
        f16x8 h = {};
        if (grow < n) {
            if constexpr (SRC_F16) {
                f16x8 v = *(const f16x8*)((const f16*)Xv + (size_t)grow * HC + g * 8);
                if constexpr (TRANS) {
#pragma unroll
                    for (int j = 0; j < 8; ++j) {
                        float f = (float)v[j];
                        f = fmaxf(fmaf(f, sc[g * 8 + j], sh[g * 8 + j]), 0.f);
                        h[j] = (f16)f;
                    }
                } else h = v;
            } else {
                const float* X = (const float*)Xv;
                float4 a = *(const float4*)(X + (size_t)grow * HC + g * 8);
                float4 c = *(const float4*)(X + (size_t)grow * HC + g * 8 + 4);
                h[0] = (f16)a.x; h[1] = (f16)a.y; h[2] = (f16)a.z; h[3] = (f16)a.w;
                h[4] = (f16)c.x; h[5] = (f16)c.y; h[6] = (f16)c.z; h[7] = (f16)c.w;
            }
        }
        *(f16x8*)&Ah[r][g * 8] = h;
    }
    __syncthreads();

    const int wv   = tid >> 6;
    const int lane = tid & 63;
    const int m    = lane & 15;
    const int kq   = (lane >> 4) * 8;

    f32x4 acc[8] = {};
#pragma unroll
    for (int kc = 0; kc < HC; kc += 32) {
        f16x8 a = *(const f16x8*)&Ah[wv * 16 + m][kc + kq];
#pragma unroll
        for (int t = 0; t < 8; ++t) {
            f16x8 b = *(const f16x8*)&Bh[t * 16 + m][kc + kq];
            acc[t] = __builtin_amdgcn_mfma_f32_16x16x32_f16(a, b, acc[t], 0, 0, 0);
        }
    }

    const int rbase = row0 + wv * 16 + (lane >> 4) * 4;
#pragma unroll
    for (int r = 0; r < 4; ++r) {
        int grow = rbase + r;
        if (grow < n) {
            float dv = dis[grow];
#pragma unroll
            for (int t = 0; t < 8; ++t)
                Y[(size_t)grow * HC + t * 16 + m] = (f16)(acc[t][r] * dv);
        }
    }
}

// ---------------- CSR gather agg, 8 edges in flight (VGPR 32, occ 64%) ------
// xws[s] = dis[s]*xw[s]; out[v] = dis[v]*(sum_e xws[s] + xws[v]) + b.
__global__ __launch_bounds__(256) void gcn_agg_f16(const f16* __restrict__ xws,
                                                   const int* __restrict__ srcs,
                                                   const int* __restrict__ rowptr,
                                                   const float* __restrict__ dis,
                                                   const float* __restrict__ bias,
                                                   f16* __restrict__ out,
                                                   float* __restrict__ stats,
                                                   int n, int nwaves) {
    __shared__ float lds_s[4][128], lds_q[4][128];
    const int wv   = threadIdx.x >> 6;
    const int lane = threadIdx.x & 63;
    const int g    = lane >> 4;      // edge subgroup 0..3
    const int cg   = lane & 15;      // channel group (8 channels)

    float b8[8];
#pragma unroll
    for (int j = 0; j < 8; ++j) b8[j] = bias[cg * 8 + j];

    float s8[8] = {}, q8[8] = {};

    for (int node = blockIdx.x * 4 + wv; node < n; node += nwaves) {
        const int e0 = rowptr[node];
        const int e1 = rowptr[node + 1];
        float acc[8] = {};
        for (int e = e0; e < e1; e += 8) {
            int i0 = e + g, i1 = e + g + 4;
            int s0 = (i0 < e1) ? srcs[i0] : n;
            int s1 = (i1 < e1) ? srcs[i1] : n;
            f16x8 v0 = *(const f16x8*)(xws + (size_t)s0 * HC + cg * 8);
            f16x8 v1 = *(const f16x8*)(xws + (size_t)s1 * HC + cg * 8);
#pragma unroll
            for (int j = 0; j < 8; ++j) {
                acc[j] += (float)v0[j];
                acc[j] += (float)v1[j];
            }
        }
#pragma unroll
        for (int j = 0; j < 8; ++j) acc[j] += __shfl_xor(acc[j], 16);
#pragma unroll
        for (int j = 0; j < 8; ++j) acc[j] += __shfl_xor(acc[j], 32);

        if (g == 0) {
            float dv = dis[node];
            f16x8 self = *(const f16x8*)(xws + (size_t)node * HC + cg * 8);
            f16x8 o;
#pragma unroll
            for (int j = 0; j < 8; ++j) {
                float r = fmaf(acc[j] + (float)self[j], dv, b8[j]);
                o[j] = (f16)r;
                s8[j] += r;
                q8[j] += r * r;
            }
            *(f16x8*)(out + (size_t)node * HC + cg * 8) = o;
        }
    }

    if (g == 0) {
#pragma unroll
        for (int j = 0; j < 8; ++j) {
            lds_s[wv][cg * 8 + j] = s8[j];
            lds_q[wv][cg * 8 + j] = q8[j];
        }
    }
    __syncthreads();
    float* stripe = stats + (size_t)(blockIdx.x & (NSTRIPE - 1)) * 256;
    if (threadIdx.x < 128) {
        float s = lds_s[0][threadIdx.x] + lds_s[1][threadIdx.x] +
                  lds_s[2][threadIdx.x] + lds_s[3][threadIdx.x];
        float q = lds_q[0][threadIdx.x] + lds_q[1][threadIdx.x] +
                  lds_q[2][threadIdx.x] + lds_q[3][threadIdx.x];
        atomicAdd(&stripe[threadIdx.x], s);
        atomicAdd(&stripe[128 + threadIdx.x], q);
    }
}

// ---------------- MFMA MLP head (BN2 finalize + BN+ReLU + both layers) ------
__global__ __launch_bounds__(256) void mlp_mfma(const f16* __restrict__ h,
                                                const float* __restrict__ stats,
                                                const float* __restrict__ gamma,
                                                const float* __restrict__ beta,
                                                const f16* __restrict__ Wm1t,
                                                const float* __restrict__ bm1,
                                                const float* __restrict__ Wm2,
                                                const float* __restrict__ bm2,
                                                float* __restrict__ out, int n) {
    __shared__ f16 Hs[64][136];
    __shared__ f16 Ws[64][136];
    __shared__ float sc[HC], sh[HC], bmv[64], w2v[64];
    const int tid  = threadIdx.x;
    const int row0 = blockIdx.x * 64;

    if (tid < 128) {
        float s = 0.f, q = 0.f;
#pragma unroll
        for (int t = 0; t < NSTRIPE; ++t) {
            s += stats[t * 256 + tid];
            q += stats[t * 256 + 128 + tid];
        }
        float m = s / (float)n;
        float v = q / (float)n - m * m;
        float scv = gamma[tid] * rsqrtf(fmaxf(v, 0.f) + EPS_BN);
        sc[tid] = scv;
        sh[tid] = beta[tid] - m * scv;
    }
    if (tid < 64) { bmv[tid] = bm1[tid]; w2v[tid] = Wm2[tid]; }

#pragma unroll
    for (int i = 0; i < 4; ++i) {
        int idx = i * 256 + tid;
        int r = idx >> 4, g = idx & 15;
        *(f16x8*)&Ws[r][g * 8] = *(const f16x8*)(Wm1t + (size_t)r * HC + g * 8);
    }
    __syncthreads();

#pragma unroll
    for (int i = 0; i < 4; ++i) {
        int idx = i * 256 + tid;
        int r = idx >> 4, g = idx & 15;
        int grow = row0 + r;
        f16x8 hv = {};
        if (grow < n) {
            f16x8 v = *(const f16x8*)(h + (size_t)grow * HC + g * 8);
#pragma unroll
            for (int j = 0; j < 8; ++j) {
                float f = (float)v[j];
                f = fmaxf(fmaf(f, sc[g * 8 + j], sh[g * 8 + j]), 0.f);
                hv[j] = (f16)f;
            }
        }
        *(f16x8*)&Hs[r][g * 8] = hv;
    }
    __syncthreads();

    const int wv   = tid >> 6;
    const int lane = tid & 63;
    const int m    = lane & 15;
    const int kq   = (lane >> 4) * 8;

    f32x4 acc[4] = {};
#pragma unroll
    for (int kc = 0; kc < HC; kc += 32) {
        f16x8 a = *(const f16x8*)&Hs[wv * 16 + m][kc + kq];
#pragma unroll
        for (int t = 0; t < 4; ++t) {
            f16x8 b = *(const f16x8*)&Ws[t * 16 + m][kc + kq];
            acc[t] = __builtin_amdgcn_mfma_f32_16x16x32_f16(a, b, acc[t], 0, 0, 0);
        }
    }

    float part[4];
#pragma unroll
    for (int reg = 0; reg < 4; ++reg) {
        float s = 0.f;
#pragma unroll
        for (int t = 0; t < 4; ++t) {
            int col = t * 16 + m;
            s += fmaxf(acc[t][reg] + bmv[col], 0.f) * w2v[col];
        }
        part[reg] = s;
    }
#pragma unroll
    for (int off = 1; off < 16; off <<= 1) {
#pragma unroll
        for (int reg = 0; reg < 4; ++reg)
            part[reg] += __shfl_xor(part[reg], off);
    }
    if (m == 0) {
        int rbase = row0 + wv * 16 + (lane >> 4) * 4;
        float bb = bm2[0];
#pragma unroll
        for (int reg = 0; reg < 4; ++reg) {
            int row = rbase + reg;
            if (row < n) out[row] = part[reg] + bb;
        }
    }
}

extern "C" void kernel_launch(void* const* d_in, const int* in_sizes, int n_in,
                              void* d_out, int out_size, void* d_ws, size_t ws_size,
                              hipStream_t stream) {
    const float* x   = (const float*)d_in[0];
    const int*   ei  = (const int*)  d_in[1];
    const float* W1  = (const float*)d_in[2];
    const float* b1  = (const float*)d_in[3];
    const float* g1  = (const float*)d_in[4];
    const float* be1 = (const float*)d_in[5];
    const float* W2  = (const float*)d_in[6];
    const float* b2  = (const float*)d_in[7];
    const float* g2  = (const float*)d_in[8];
    const float* be2 = (const float*)d_in[9];
    const float* Wm1 = (const float*)d_in[10];
    const float* bm1 = (const float*)d_in[11];
    const float* Wm2 = (const float*)d_in[12];
    const float* bm2 = (const float*)d_in[13];
    float* out = (float*)d_out;

    const int n = in_sizes[0] / HC;       // 100000
    const int E = in_sizes[1] / 2;        // 1600000
    const int* srcp = ei;
    const int* dstp = ei + E;
    const int nb = (n + BNODES - 1) >> BSHIFT;   // 196 buckets

    char* ws = (char*)d_ws;
    size_t off = 0;
    auto alloc = [&](size_t bytes) { void* p = ws + off; off = (off + bytes + 511) & ~511ULL; return p; };
    float*  dis    = (float*) alloc((size_t)n * 4);
    int*    rowptr = (int*)   alloc((size_t)(n + 1) * 4);
    // contiguous zero region: bcnt(256) | stats1(2048) | stats2(2048) floats
    int*    zreg   = (int*)   alloc((256 + 2 * NSTRIPE * 256) * 4);
    int*    bcnt   = zreg;
    float*  stats1 = (float*)(zreg + 256);
    float*  stats2 = stats1 + NSTRIPE * 256;
    int*    bbase  = (int*)   alloc(1024 + 4);
    int*    gcur   = (int*)   alloc(1024);
    unsigned int* packed = (unsigned int*)alloc((size_t)E * 4);
    int*    srcs   = (int*)   alloc((size_t)E * 4);
    f16*    xws    = (f16*)   alloc((size_t)(n + 1) * HC * 2);   // +1 zero pad row
    f16*    bufBh  = (f16*)   alloc((size_t)n * HC * 2);
    f16*    Wt1    = (f16*)   alloc((size_t)HC * HC * 2);
    f16*    Wt2    = (f16*)   alloc((size_t)HC * HC * 2);
    f16*    Wm1t   = (f16*)   alloc((size_t)64 * HC * 2);

    const int gemmBlocks = (n + 63) / 64;
    const int binBlocks  = (E + CHUNK - 1) / CHUNK;
    const int aggWaves   = AGG_BLOCKS * 4;

    // ---- single fused zero init ----
    hipMemsetAsync(zreg, 0, (256 + 2 * NSTRIPE * 256) * 4, stream);

    // ---- CSR build: bucket histogram -> scan -> bin -> per-bucket sort ----
    bucket_count<<<binBlocks, 1024, 0, stream>>>(dstp, bcnt, E);
    bscan<<<1, 256, 0, stream>>>(bcnt, bbase, gcur, rowptr, nb, n, E);
    edge_bin<<<binBlocks, 1024, 0, stream>>>(srcp, dstp, gcur, packed, E);
    edge_sort<<<nb, 1024, 0, stream>>>(packed, bbase, rowptr, dis, srcs, n);

    // ---- weight prep + pad row zero ----
    wprep_all<<<(41088 + 255) / 256, 256, 0, stream>>>(W1, W2, Wm1, Wt1, Wt2, Wm1t,
                                                       xws + (size_t)n * HC);

    // ---- layer 1 ----
    gemm_mfma<0, 0><<<gemmBlocks, 256, 0, stream>>>(x, Wt1, nullptr, nullptr, nullptr,
                                                    dis, xws, n);
    gcn_agg_f16<<<AGG_BLOCKS, 256, 0, stream>>>(xws, srcs, rowptr, dis, b1,
                                                bufBh, stats1, n, aggWaves);

    // ---- layer 2 (BN1 finalize + BN+ReLU fused into GEMM staging) ----
    gemm_mfma<1, 1><<<gemmBlocks, 256, 0, stream>>>(bufBh, Wt2, stats1, g1, be1,
                                                    dis, xws, n);
    gcn_agg_f16<<<AGG_BLOCKS, 256, 0, stream>>>(xws, srcs, rowptr, dis, b2,
                                                bufBh, stats2, n, aggWaves);

    // ---- MLP head (BN2 finalize + BN+ReLU + both layers fused, MFMA) ----
    mlp_mfma<<<gemmBlocks, 256, 0, stream>>>(bufBh, stats2, g2, be2, Wm1t, bm1, Wm2, bm2,
                                             out, n);
}